// Round 2
// baseline (783.976 us; speedup 1.0000x reference)
//
#include <hip/hip_runtime.h>
#include <hip/hip_bf16.h>

typedef __hip_bfloat16 bf16;

#define TSEQ   2048
#define DMODEL 1024
#define NHEAD  16
#define QKV_W  3072   // cols: [0,512) qs | [512,1024) ks | [1024,1536) qg | [1536,2048) kg | [2048,3072) v
#define SCALE  0.17677669529663687f  // 1/sqrt(32), sem_scale == geo_scale

// ---------------------------------------------------------------------------
// Projection GEMM: qkv[2048][3072] (bf16) = X[2048][1024] (f32) @ [Wqs|Wks|Wqg|Wkg|Wv] (f32)
// f32 accumulate. 64x64 tile, BK=16, 4x4 micro-tile.
// ---------------------------------------------------------------------------
__global__ __launch_bounds__(256) void proj_gemm(
    const float* __restrict__ X,
    const float* __restrict__ Wqs, const float* __restrict__ Wks,
    const float* __restrict__ Wqg, const float* __restrict__ Wkg,
    const float* __restrict__ Wv,
    bf16* __restrict__ out)
{
    __shared__ float As[16][65];   // [k][m], padded
    __shared__ float Bs[16][64];   // [k][n]
    const int n0 = blockIdx.x * 64;
    const int m0 = blockIdx.y * 64;
    const float* W; int ldw, wn;
    if (n0 < 512)       { W = Wqs; ldw = 512;  wn = n0; }
    else if (n0 < 1024) { W = Wks; ldw = 512;  wn = n0 - 512; }
    else if (n0 < 1536) { W = Wqg; ldw = 512;  wn = n0 - 1024; }
    else if (n0 < 2048) { W = Wkg; ldw = 512;  wn = n0 - 1536; }
    else                { W = Wv;  ldw = 1024; wn = n0 - 2048; }

    const int tid = threadIdx.x;
    const int tx = tid & 15, ty = tid >> 4;
    const int am = tid >> 2;           // 0..63 (row within tile)
    const int ak = (tid & 3) * 4;      // 0,4,8,12

    float acc[4][4] = {};
    for (int k0 = 0; k0 < DMODEL; k0 += 16) {
        float4 av = *(const float4*)(X + (size_t)(m0 + am) * DMODEL + k0 + ak);
        As[ak + 0][am] = av.x;
        As[ak + 1][am] = av.y;
        As[ak + 2][am] = av.z;
        As[ak + 3][am] = av.w;
        #pragma unroll
        for (int i = 0; i < 4; ++i) {
            int idx = tid + 256 * i;
            int bk = idx >> 6, bn = idx & 63;
            Bs[bk][bn] = W[(size_t)(k0 + bk) * ldw + wn + bn];
        }
        __syncthreads();
        #pragma unroll
        for (int k = 0; k < 16; ++k) {
            float a[4], b[4];
            #pragma unroll
            for (int i = 0; i < 4; ++i) a[i] = As[k][ty * 4 + i];
            #pragma unroll
            for (int j = 0; j < 4; ++j) b[j] = Bs[k][tx * 4 + j];
            #pragma unroll
            for (int i = 0; i < 4; ++i)
                #pragma unroll
                for (int j = 0; j < 4; ++j)
                    acc[i][j] += a[i] * b[j];
        }
        __syncthreads();
    }
    #pragma unroll
    for (int i = 0; i < 4; ++i)
        #pragma unroll
        for (int j = 0; j < 4; ++j)
            out[(size_t)(m0 + ty * 4 + i) * QKV_W + n0 + tx * 4 + j] =
                __float2bfloat16(acc[i][j]);
}

// ---------------------------------------------------------------------------
// RoPE in-place on qg / kg columns of the bf16 qkv buffer.
// ---------------------------------------------------------------------------
__global__ __launch_bounds__(256) void rope_kernel(bf16* __restrict__ qkv)
{
    int idx = blockIdx.x * 256 + threadIdx.x;   // < 2048*512
    int t     = idx >> 9;
    int rem   = idx & 511;
    int which = rem >> 8;            // 0 = qg, 1 = kg
    int h     = (rem >> 4) & 15;
    int i     = rem & 15;
    bf16* base = qkv + (size_t)t * QKV_W + 1024 + which * 512 + h * 32;
    // inv_freq = 10000^(-2i/32)
    float inv = __expf(-((float)(2 * i) * (1.0f / 32.0f)) * 9.210340371976184f);
    float ang = (float)t * inv;
    float c = cosf(ang), s = sinf(ang);
    float x1 = __bfloat162float(base[i]);
    float x2 = __bfloat162float(base[i + 16]);
    base[i]      = __float2bfloat16(x1 * c - x2 * s);
    base[i + 16] = __float2bfloat16(x2 * c + x1 * s);
}

// ---------------------------------------------------------------------------
// Flash attention, f32 math over bf16 qkv. Block = one head x 64 queries.
// Combined 64-dim QK dot (sem|geo share the same scale). Null key at fk==0.
// Causal: query q attends fk <= q+1.
// ---------------------------------------------------------------------------
__global__ __launch_bounds__(256) void attn_kernel(
    const bf16* __restrict__ qkv,
    const float* __restrict__ ksn, const float* __restrict__ kgn,
    const float* __restrict__ vn,
    float* __restrict__ attnout)
{
    const int h  = blockIdx.y;
    const int q0 = blockIdx.x * 64;

    __shared__ float Qt[64][65];   // [d][r]  padded
    __shared__ float Kt[64][65];   // [d][kk] padded
    __shared__ float Vs[64][64];   // [kk][d]
    __shared__ float Ss[64][65];   // [r][kk] padded
    __shared__ float mrow[64], lrow[64], arow[64];
    __shared__ float part[4][64];

    const int tid = threadIdx.x;
    const int tx = tid & 15, ty = tid >> 4;
    const int r8 = tid & 63, seg = tid >> 6;

    // Q tile (transposed into LDS)
    #pragma unroll
    for (int i = 0; i < 16; ++i) {
        int idx = tid + 256 * i;
        int d = idx & 63, r = idx >> 6;
        int col = (d < 32) ? (h * 32 + d) : (1024 + h * 32 + (d - 32));
        Qt[d][r] = __bfloat162float(qkv[(size_t)(q0 + r) * QKV_W + col]);
    }
    if (tid < 64) { mrow[tid] = -1e30f; lrow[tid] = 0.0f; }
    float acc[4][4] = {};

    const int nkb = blockIdx.x + 2;   // covers fk up to q0+127 >= q0+64
    for (int kb = 0; kb < nkb; ++kb) {
        __syncthreads();   // previous iteration done with Kt/Vs/Ss
        const int fk0 = kb * 64;
        #pragma unroll
        for (int i = 0; i < 16; ++i) {
            int idx = tid + 256 * i;
            int d = idx & 63, kk = idx >> 6;
            int fk = fk0 + kk;
            float val;
            if (fk == 0)
                val = (d < 32) ? ksn[h * 32 + d] : kgn[h * 32 + d - 32];
            else if (fk <= TSEQ) {
                int col = (d < 32) ? (512 + h * 32 + d) : (1536 + h * 32 + (d - 32));
                val = __bfloat162float(qkv[(size_t)(fk - 1) * QKV_W + col]);
            } else val = 0.0f;
            Kt[d][kk] = val;
        }
        #pragma unroll
        for (int i = 0; i < 16; ++i) {
            int idx = tid + 256 * i;
            int d = idx & 63, kk = idx >> 6;
            int fk = fk0 + kk;
            float val;
            if (fk == 0)           val = vn[h * 64 + d];
            else if (fk <= TSEQ)   val = __bfloat162float(qkv[(size_t)(fk - 1) * QKV_W + 2048 + h * 64 + d]);
            else                   val = 0.0f;
            Vs[kk][d] = val;
        }
        __syncthreads();

        // S tile: 4x4 per thread over 64 dims
        float s[4][4] = {};
        for (int d = 0; d < 64; ++d) {
            float a[4], b[4];
            #pragma unroll
            for (int i = 0; i < 4; ++i) a[i] = Qt[d][ty * 4 + i];
            #pragma unroll
            for (int j = 0; j < 4; ++j) b[j] = Kt[d][tx * 4 + j];
            #pragma unroll
            for (int i = 0; i < 4; ++i)
                #pragma unroll
                for (int j = 0; j < 4; ++j)
                    s[i][j] += a[i] * b[j];
        }
        #pragma unroll
        for (int i = 0; i < 4; ++i)
            #pragma unroll
            for (int j = 0; j < 4; ++j) {
                int q  = q0 + ty * 4 + i;
                int fk = fk0 + tx * 4 + j;
                Ss[ty * 4 + i][tx * 4 + j] = (fk <= q + 1) ? s[i][j] * SCALE : -1e9f;
            }
        __syncthreads();

        // row max (4 partials per row)
        float pm = -1e30f;
        #pragma unroll
        for (int c = 0; c < 16; ++c) pm = fmaxf(pm, Ss[r8][seg * 16 + c]);
        part[seg][r8] = pm;
        __syncthreads();
        if (seg == 0) {
            float mnew = fmaxf(fmaxf(part[0][r8], part[1][r8]),
                               fmaxf(part[2][r8], part[3][r8]));
            mnew = fmaxf(mnew, mrow[r8]);
            float al = __expf(mrow[r8] - mnew);
            arow[r8] = al;
            mrow[r8] = mnew;
            lrow[r8] *= al;
        }
        __syncthreads();

        // P = exp(S - m) in place + partial row sums; rescale O by alpha
        {
            float mn = mrow[r8];
            float ps = 0.0f;
            #pragma unroll
            for (int c = 0; c < 16; ++c) {
                float p = __expf(Ss[r8][seg * 16 + c] - mn);
                Ss[r8][seg * 16 + c] = p;
                ps += p;
            }
            part[seg][r8] = ps;
        }
        {
            float alv[4];
            #pragma unroll
            for (int i = 0; i < 4; ++i) alv[i] = arow[ty * 4 + i];
            #pragma unroll
            for (int i = 0; i < 4; ++i)
                #pragma unroll
                for (int j = 0; j < 4; ++j) acc[i][j] *= alv[i];
        }
        __syncthreads();
        if (seg == 0)
            lrow[r8] += part[0][r8] + part[1][r8] + part[2][r8] + part[3][r8];

        // O += P @ V
        for (int kk = 0; kk < 64; ++kk) {
            float p[4], v[4];
            #pragma unroll
            for (int i = 0; i < 4; ++i) p[i] = Ss[ty * 4 + i][kk];
            #pragma unroll
            for (int j = 0; j < 4; ++j) v[j] = Vs[kk][tx * 4 + j];
            #pragma unroll
            for (int i = 0; i < 4; ++i)
                #pragma unroll
                for (int j = 0; j < 4; ++j) acc[i][j] += p[i] * v[j];
        }
    }
    __syncthreads();   // lrow final

    #pragma unroll
    for (int i = 0; i < 4; ++i) {
        float inv_l = 1.0f / lrow[ty * 4 + i];
        #pragma unroll
        for (int j = 0; j < 4; ++j)
            attnout[(size_t)(q0 + ty * 4 + i) * DMODEL + h * 64 + tx * 4 + j] =
                acc[i][j] * inv_l;
    }
}

// ---------------------------------------------------------------------------
// Output GEMM: out[2048][1024] (f32) = attn[2048][1024] (f32) @ Wo[1024][1024] (f32)
// ---------------------------------------------------------------------------
__global__ __launch_bounds__(256) void out_gemm(
    const float* __restrict__ A,
    const float* __restrict__ Wo,
    float* __restrict__ C)
{
    __shared__ float As[16][65];
    __shared__ float Bs[16][64];
    const int n0 = blockIdx.x * 64;
    const int m0 = blockIdx.y * 64;
    const int tid = threadIdx.x;
    const int tx = tid & 15, ty = tid >> 4;
    const int am = tid >> 2;
    const int ak = (tid & 3) * 4;

    float acc[4][4] = {};
    for (int k0 = 0; k0 < DMODEL; k0 += 16) {
        float4 av = *(const float4*)(A + (size_t)(m0 + am) * DMODEL + k0 + ak);
        As[ak + 0][am] = av.x;
        As[ak + 1][am] = av.y;
        As[ak + 2][am] = av.z;
        As[ak + 3][am] = av.w;
        #pragma unroll
        for (int i = 0; i < 4; ++i) {
            int idx = tid + 256 * i;
            int bk = idx >> 6, bn = idx & 63;
            Bs[bk][bn] = Wo[(size_t)(k0 + bk) * DMODEL + n0 + bn];
        }
        __syncthreads();
        #pragma unroll
        for (int k = 0; k < 16; ++k) {
            float a[4], b[4];
            #pragma unroll
            for (int i = 0; i < 4; ++i) a[i] = As[k][ty * 4 + i];
            #pragma unroll
            for (int j = 0; j < 4; ++j) b[j] = Bs[k][tx * 4 + j];
            #pragma unroll
            for (int i = 0; i < 4; ++i)
                #pragma unroll
                for (int j = 0; j < 4; ++j)
                    acc[i][j] += a[i] * b[j];
        }
        __syncthreads();
    }
    #pragma unroll
    for (int i = 0; i < 4; ++i)
        #pragma unroll
        for (int j = 0; j < 4; ++j)
            C[(size_t)(m0 + ty * 4 + i) * DMODEL + n0 + tx * 4 + j] = acc[i][j];
}

// ---------------------------------------------------------------------------
extern "C" void kernel_launch(void* const* d_in, const int* in_sizes, int n_in,
                              void* d_out, int out_size, void* d_ws, size_t ws_size,
                              hipStream_t stream)
{
    const float* x      = (const float*)d_in[0];
    const float* wq_sem = (const float*)d_in[1];
    const float* wk_sem = (const float*)d_in[2];
    const float* wq_geo = (const float*)d_in[3];
    const float* wk_geo = (const float*)d_in[4];
    const float* wv     = (const float*)d_in[5];
    const float* wo     = (const float*)d_in[6];
    const float* ksn    = (const float*)d_in[7];
    const float* kgn    = (const float*)d_in[8];
    const float* vn     = (const float*)d_in[9];
    float* out = (float*)d_out;

    bf16*  qkv  = (bf16*)d_ws;                               // 2048*3072 bf16 = 12.6 MB
    float* attn = (float*)((char*)d_ws + (size_t)TSEQ * QKV_W * sizeof(bf16)); // 8.4 MB

    proj_gemm<<<dim3(QKV_W / 64, TSEQ / 64), 256, 0, stream>>>(
        x, wq_sem, wk_sem, wq_geo, wk_geo, wv, qkv);
    rope_kernel<<<(TSEQ * 512) / 256, 256, 0, stream>>>(qkv);
    attn_kernel<<<dim3(TSEQ / 64, NHEAD), 256, 0, stream>>>(qkv, ksn, kgn, vn, attn);
    out_gemm<<<dim3(DMODEL / 64, TSEQ / 64), 256, 0, stream>>>(attn, wo, out);
}

// Round 3
// 173.372 us; speedup vs baseline: 4.5219x; 4.5219x over previous
//
#include <hip/hip_runtime.h>
#include <hip/hip_bf16.h>

typedef __hip_bfloat16 bf16;
typedef __attribute__((ext_vector_type(8))) short bf16x8;   // 8 bf16 = 4 VGPR (MFMA A/B frag)
typedef __attribute__((ext_vector_type(4))) float f32x4;    // MFMA C/D frag

#define TSEQ   2048
#define DMODEL 1024
#define NHEAD  16
#define QKV_W  3072   // [0,512) qs | [512,1024) ks | [1024,1536) qg | [1536,2048) kg | [2048,3072) v
#define SCALE  0.17677669529663687f  // 1/sqrt(32) == sem_scale == geo_scale

__device__ __forceinline__ unsigned short f2bf(float f) {
    union { bf16 h; unsigned short u; } x;
    x.h = __float2bfloat16(f);
    return x.u;
}

__device__ __forceinline__ void gload_lds16(const void* g, void* l) {
    __builtin_amdgcn_global_load_lds(
        (const __attribute__((address_space(1))) void*)g,
        (__attribute__((address_space(3))) void*)l, 16, 0, 0);
}

// ---------------------------------------------------------------------------
// Prep: f32 -> bf16 convert of X
// ---------------------------------------------------------------------------
__global__ __launch_bounds__(256) void convert_x(const float* __restrict__ X,
                                                 unsigned short* __restrict__ Xb)
{
    int i = (blockIdx.x * 256 + threadIdx.x) * 4;
    float4 v = *(const float4*)(X + i);
    ushort4 o;
    o.x = f2bf(v.x); o.y = f2bf(v.y); o.z = f2bf(v.z); o.w = f2bf(v.w);
    *(ushort4*)(Xb + i) = o;
}

// ---------------------------------------------------------------------------
// Prep: transpose + convert  dst[C][1024] (bf16) = src[1024][C] (f32)^T
// ---------------------------------------------------------------------------
__global__ __launch_bounds__(256) void transpose_w(const float* __restrict__ src,
                                                   unsigned short* __restrict__ dst,
                                                   int C)
{
    __shared__ float T[64][65];
    const int c0 = blockIdx.x * 64, r0 = blockIdx.y * 64;
    const int tid = threadIdx.x;
    #pragma unroll
    for (int i = 0; i < 16; ++i) {
        int idx = tid + 256 * i;
        int r = idx >> 6, c = idx & 63;
        T[r][c] = src[(size_t)(r0 + r) * C + c0 + c];
    }
    __syncthreads();
    #pragma unroll
    for (int i = 0; i < 16; ++i) {
        int idx = tid + 256 * i;
        int cc = idx >> 6, rr = idx & 63;
        dst[(size_t)(c0 + cc) * 1024 + r0 + rr] = f2bf(T[rr][cc]);
    }
}

// ---------------------------------------------------------------------------
// MFMA GEMM (m97 structure): C[M][ldc] = A[M][1024] * Bt[N][1024]^T
// 128x128 tile, BK=32, 4 waves (2x2), 4x4 16x16x32 frags per wave.
// ---------------------------------------------------------------------------
__global__ __launch_bounds__(256) void gemm_proj(const unsigned short* __restrict__ A,
                                                 const unsigned short* __restrict__ Bt,
                                                 unsigned short* __restrict__ C)
{
    __shared__ __align__(16) unsigned short Abuf[128 * 32];
    __shared__ __align__(16) unsigned short Bbuf[128 * 32];
    const int n0 = blockIdx.x * 128, m0 = blockIdx.y * 128;
    const int tid = threadIdx.x, l = tid & 63, wv = tid >> 6;
    const int wr = wv >> 1, wc = wv & 1;
    const int lr = l & 15, kf = (l >> 4) * 8;

    f32x4 acc[4][4];
    #pragma unroll
    for (int i = 0; i < 4; ++i)
        #pragma unroll
        for (int j = 0; j < 4; ++j) acc[i][j] = (f32x4){0.f, 0.f, 0.f, 0.f};

    for (int k0 = 0; k0 < 1024; k0 += 32) {
        #pragma unroll
        for (int it = 0; it < 2; ++it) {
            int c = it * 256 + wv * 64 + l;
            int row = c >> 2, seg = c & 3;
            gload_lds16(A  + (size_t)(m0 + row) * 1024 + k0 + seg * 8,
                        &Abuf[(it * 256 + wv * 64) * 8]);
            gload_lds16(Bt + (size_t)(n0 + row) * 1024 + k0 + seg * 8,
                        &Bbuf[(it * 256 + wv * 64) * 8]);
        }
        __syncthreads();
        bf16x8 af[4], bfv[4];
        #pragma unroll
        for (int mf = 0; mf < 4; ++mf)
            af[mf] = *(const bf16x8*)&Abuf[(wr * 64 + mf * 16 + lr) * 32 + kf];
        #pragma unroll
        for (int nf = 0; nf < 4; ++nf)
            bfv[nf] = *(const bf16x8*)&Bbuf[(wc * 64 + nf * 16 + lr) * 32 + kf];
        #pragma unroll
        for (int mf = 0; mf < 4; ++mf)
            #pragma unroll
            for (int nf = 0; nf < 4; ++nf)
                acc[mf][nf] = __builtin_amdgcn_mfma_f32_16x16x32_bf16(
                    af[mf], bfv[nf], acc[mf][nf], 0, 0, 0);
        __syncthreads();
    }
    #pragma unroll
    for (int mf = 0; mf < 4; ++mf)
        #pragma unroll
        for (int nf = 0; nf < 4; ++nf)
            #pragma unroll
            for (int reg = 0; reg < 4; ++reg) {
                int row = m0 + wr * 64 + mf * 16 + (l >> 4) * 4 + reg;
                int col = n0 + wc * 64 + nf * 16 + lr;
                C[(size_t)row * QKV_W + col] = f2bf(acc[mf][nf][reg]);
            }
}

__global__ __launch_bounds__(256) void gemm_out(const unsigned short* __restrict__ A,
                                                const unsigned short* __restrict__ Bt,
                                                float* __restrict__ C)
{
    __shared__ __align__(16) unsigned short Abuf[128 * 32];
    __shared__ __align__(16) unsigned short Bbuf[128 * 32];
    const int n0 = blockIdx.x * 128, m0 = blockIdx.y * 128;
    const int tid = threadIdx.x, l = tid & 63, wv = tid >> 6;
    const int wr = wv >> 1, wc = wv & 1;
    const int lr = l & 15, kf = (l >> 4) * 8;

    f32x4 acc[4][4];
    #pragma unroll
    for (int i = 0; i < 4; ++i)
        #pragma unroll
        for (int j = 0; j < 4; ++j) acc[i][j] = (f32x4){0.f, 0.f, 0.f, 0.f};

    for (int k0 = 0; k0 < 1024; k0 += 32) {
        #pragma unroll
        for (int it = 0; it < 2; ++it) {
            int c = it * 256 + wv * 64 + l;
            int row = c >> 2, seg = c & 3;
            gload_lds16(A  + (size_t)(m0 + row) * 1024 + k0 + seg * 8,
                        &Abuf[(it * 256 + wv * 64) * 8]);
            gload_lds16(Bt + (size_t)(n0 + row) * 1024 + k0 + seg * 8,
                        &Bbuf[(it * 256 + wv * 64) * 8]);
        }
        __syncthreads();
        bf16x8 af[4], bfv[4];
        #pragma unroll
        for (int mf = 0; mf < 4; ++mf)
            af[mf] = *(const bf16x8*)&Abuf[(wr * 64 + mf * 16 + lr) * 32 + kf];
        #pragma unroll
        for (int nf = 0; nf < 4; ++nf)
            bfv[nf] = *(const bf16x8*)&Bbuf[(wc * 64 + nf * 16 + lr) * 32 + kf];
        #pragma unroll
        for (int mf = 0; mf < 4; ++mf)
            #pragma unroll
            for (int nf = 0; nf < 4; ++nf)
                acc[mf][nf] = __builtin_amdgcn_mfma_f32_16x16x32_bf16(
                    af[mf], bfv[nf], acc[mf][nf], 0, 0, 0);
        __syncthreads();
    }
    #pragma unroll
    for (int mf = 0; mf < 4; ++mf)
        #pragma unroll
        for (int nf = 0; nf < 4; ++nf)
            #pragma unroll
            for (int reg = 0; reg < 4; ++reg) {
                int row = m0 + wr * 64 + mf * 16 + (l >> 4) * 4 + reg;
                int col = n0 + wc * 64 + nf * 16 + lr;
                C[(size_t)row * DMODEL + col] = acc[mf][nf][reg];
            }
}

// ---------------------------------------------------------------------------
// RoPE in-place on qg / kg columns of the bf16 qkv buffer.
// ---------------------------------------------------------------------------
__global__ __launch_bounds__(256) void rope_kernel(bf16* __restrict__ qkv)
{
    int idx = blockIdx.x * 256 + threadIdx.x;   // < 2048*512
    int t     = idx >> 9;
    int rem   = idx & 511;
    int which = rem >> 8;
    int h     = (rem >> 4) & 15;
    int i     = rem & 15;
    bf16* base = qkv + (size_t)t * QKV_W + 1024 + which * 512 + h * 32;
    float inv = __expf(-((float)(2 * i) * (1.0f / 32.0f)) * 9.210340371976184f);
    float ang = (float)t * inv;
    float c = cosf(ang), s = sinf(ang);
    float x1 = __bfloat162float(base[i]);
    float x2 = __bfloat162float(base[i + 16]);
    base[i]      = __float2bfloat16(x1 * c - x2 * s);
    base[i + 16] = __float2bfloat16(x2 * c + x1 * s);
}

// ---------------------------------------------------------------------------
// MFMA flash attention. Block = 1 head x 64 queries, 4 waves x 16 rows, KB=64.
// Combined 64-d QK (sem|geo, shared scale). Null key at fk==0; causal fk<=q+1.
// All LDS tiles XOR-swizzled: elem (row, c) at row*64 + (c ^ ((row&7)<<3)).
// ---------------------------------------------------------------------------
__global__ __launch_bounds__(256) void attn_mfma(
    const unsigned short* __restrict__ qkv,
    const float* __restrict__ ksn, const float* __restrict__ kgn,
    const float* __restrict__ vn,
    unsigned short* __restrict__ attnO)
{
    __shared__ __align__(16) unsigned short Ks[64 * 64];  // [kk][d]
    __shared__ __align__(16) unsigned short Vt[64 * 64];  // [dv][kk]
    __shared__ __align__(16) unsigned short Ps[64 * 64];  // [q][kk]

    const int h  = blockIdx.y;
    const int qb = gridDim.x - 1 - blockIdx.x;   // heavy (high-q) blocks first
    const int q0 = qb * 64;
    const int tid = threadIdx.x, l = tid & 63, w = tid >> 6;
    const int lr = l & 15, lg = l >> 4;

    // Q fragments in registers (A-frag: row=lane&15, k=(lane>>4)*8)
    const int qrow = q0 + w * 16 + lr;
    const int d0 = lg * 8;
    bf16x8 qa0 = *(const bf16x8*)&qkv[(size_t)qrow * QKV_W + h * 32 + d0];          // sem d0..d0+8
    bf16x8 qa1 = *(const bf16x8*)&qkv[(size_t)qrow * QKV_W + 1024 + h * 32 + d0];   // geo d-32

    f32x4 o[4];
    #pragma unroll
    for (int i = 0; i < 4; ++i) o[i] = (f32x4){0.f, 0.f, 0.f, 0.f};
    float m[4]  = {-1e30f, -1e30f, -1e30f, -1e30f};
    float ll[4] = {0.f, 0.f, 0.f, 0.f};

    const int nkb = qb + 2;
    for (int kb = 0; kb < nkb; ++kb) {
        __syncthreads();            // previous PV done before restaging Ks/Vt
        const int fk0 = kb * 64;

        // ---- stage K tile [kk][d], swizzled
        {
            int kk = tid >> 2, dq = (tid & 3) * 16;
            int fk = fk0 + kk;
            #pragma unroll
            for (int half = 0; half < 2; ++half) {
                int dd = dq + half * 8;
                unsigned short vbuf[8];
                if (fk == 0) {
                    #pragma unroll
                    for (int j = 0; j < 8; ++j) {
                        int d = dd + j;
                        vbuf[j] = f2bf(d < 32 ? ksn[h * 32 + d] : kgn[h * 32 + d - 32]);
                    }
                } else if (fk <= TSEQ) {
                    int col = (dd < 32) ? (512 + h * 32 + dd) : (1536 + h * 32 + dd - 32);
                    const bf16x8 t = *(const bf16x8*)&qkv[(size_t)(fk - 1) * QKV_W + col];
                    *(bf16x8*)vbuf = t;
                } else {
                    #pragma unroll
                    for (int j = 0; j < 8; ++j) vbuf[j] = 0;
                }
                int off = kk * 64 + (dd ^ ((kk & 7) << 3));
                *(bf16x8*)&Ks[off] = *(bf16x8*)vbuf;
            }
        }
        // ---- stage V^T tile [dv][kk], swizzled (coalesced 2B row reads)
        {
            int dv = tid & 63, kkq = (tid >> 6) * 16;
            unsigned short vbuf[16];
            #pragma unroll
            for (int j = 0; j < 16; ++j) {
                int fk = fk0 + kkq + j;
                unsigned short u;
                if (fk == 0)            u = f2bf(vn[h * 64 + dv]);
                else if (fk <= TSEQ)    u = qkv[(size_t)(fk - 1) * QKV_W + 2048 + h * 64 + dv];
                else                    u = 0;
                vbuf[j] = u;
            }
            int off0 = dv * 64 + (kkq ^ ((dv & 7) << 3));
            int off1 = dv * 64 + ((kkq + 8) ^ ((dv & 7) << 3));
            *(bf16x8*)&Vt[off0] = *(bf16x8*)&vbuf[0];
            *(bf16x8*)&Vt[off1] = *(bf16x8*)&vbuf[8];
        }
        __syncthreads();

        // ---- QK^T: S[q][kk], wave w owns rows w*16..+16, 4 col-frags
        f32x4 sa[4];
        #pragma unroll
        for (int i = 0; i < 4; ++i) sa[i] = (f32x4){0.f, 0.f, 0.f, 0.f};
        #pragma unroll
        for (int ks = 0; ks < 2; ++ks) {
            int dd = lg * 8 + ks * 32;
            bf16x8 qa = ks ? qa1 : qa0;
            #pragma unroll
            for (int nf = 0; nf < 4; ++nf) {
                int kkc = nf * 16 + lr;
                bf16x8 kbf = *(const bf16x8*)&Ks[kkc * 64 + (dd ^ ((kkc & 7) << 3))];
                sa[nf] = __builtin_amdgcn_mfma_f32_16x16x32_bf16(qa, kbf, sa[nf], 0, 0, 0);
            }
        }

        // ---- mask + scale + online softmax (in-register)
        float sv[4][4];
        float mt[4] = {-1e30f, -1e30f, -1e30f, -1e30f};
        #pragma unroll
        for (int nf = 0; nf < 4; ++nf)
            #pragma unroll
            for (int reg = 0; reg < 4; ++reg) {
                int q  = q0 + w * 16 + lg * 4 + reg;
                int fk = fk0 + nf * 16 + lr;
                float val = (fk <= q + 1) ? sa[nf][reg] * SCALE : -1e9f;
                sv[nf][reg] = val;
                mt[reg] = fmaxf(mt[reg], val);
            }
        #pragma unroll
        for (int reg = 0; reg < 4; ++reg) {
            #pragma unroll
            for (int off = 1; off < 16; off <<= 1)
                mt[reg] = fmaxf(mt[reg], __shfl_xor(mt[reg], off, 64));
        }
        float alpha[4], rs[4];
        #pragma unroll
        for (int reg = 0; reg < 4; ++reg) {
            float mn = fmaxf(m[reg], mt[reg]);
            alpha[reg] = __expf(m[reg] - mn);
            m[reg] = mn;
        }
        #pragma unroll
        for (int nf = 0; nf < 4; ++nf)
            #pragma unroll
            for (int reg = 0; reg < 4; ++reg)
                sv[nf][reg] = __expf(sv[nf][reg] - m[reg]);
        #pragma unroll
        for (int reg = 0; reg < 4; ++reg) {
            rs[reg] = sv[0][reg] + sv[1][reg] + sv[2][reg] + sv[3][reg];
            #pragma unroll
            for (int off = 1; off < 16; off <<= 1)
                rs[reg] += __shfl_xor(rs[reg], off, 64);
            ll[reg] = ll[reg] * alpha[reg] + rs[reg];
        }
        #pragma unroll
        for (int nf = 0; nf < 4; ++nf)
            #pragma unroll
            for (int reg = 0; reg < 4; ++reg)
                o[nf][reg] *= alpha[reg];

        // ---- P -> bf16 -> LDS (swizzled)
        #pragma unroll
        for (int nf = 0; nf < 4; ++nf)
            #pragma unroll
            for (int reg = 0; reg < 4; ++reg) {
                int r  = w * 16 + lg * 4 + reg;
                int kk = nf * 16 + lr;
                Ps[r * 64 + (kk ^ ((r & 7) << 3))] = f2bf(sv[nf][reg]);
            }
        __syncthreads();

        // ---- PV: O += P @ V
        #pragma unroll
        for (int ks = 0; ks < 2; ++ks) {
            int kk0 = lg * 8 + ks * 32;
            int pr  = w * 16 + lr;
            bf16x8 pa = *(const bf16x8*)&Ps[pr * 64 + (kk0 ^ ((pr & 7) << 3))];
            #pragma unroll
            for (int nf = 0; nf < 4; ++nf) {
                int dv = nf * 16 + lr;
                bf16x8 vb = *(const bf16x8*)&Vt[dv * 64 + (kk0 ^ ((dv & 7) << 3))];
                o[nf] = __builtin_amdgcn_mfma_f32_16x16x32_bf16(pa, vb, o[nf], 0, 0, 0);
            }
        }
    }

    float inv[4];
    #pragma unroll
    for (int reg = 0; reg < 4; ++reg) inv[reg] = 1.0f / ll[reg];
    #pragma unroll
    for (int nf = 0; nf < 4; ++nf)
        #pragma unroll
        for (int reg = 0; reg < 4; ++reg) {
            int q = q0 + w * 16 + lg * 4 + reg;
            attnO[(size_t)q * DMODEL + h * 64 + nf * 16 + lr] = f2bf(o[nf][reg] * inv[reg]);
        }
}

// ---------------------------------------------------------------------------
extern "C" void kernel_launch(void* const* d_in, const int* in_sizes, int n_in,
                              void* d_out, int out_size, void* d_ws, size_t ws_size,
                              hipStream_t stream)
{
    const float* x      = (const float*)d_in[0];
    const float* wq_sem = (const float*)d_in[1];
    const float* wk_sem = (const float*)d_in[2];
    const float* wq_geo = (const float*)d_in[3];
    const float* wk_geo = (const float*)d_in[4];
    const float* wv     = (const float*)d_in[5];
    const float* wo     = (const float*)d_in[6];
    const float* ksn    = (const float*)d_in[7];
    const float* kgn    = (const float*)d_in[8];
    const float* vn     = (const float*)d_in[9];
    float* out = (float*)d_out;

    char* ws = (char*)d_ws;
    unsigned short* Xb    = (unsigned short*)(ws);                       //  4.19 MB
    unsigned short* WcatT = (unsigned short*)(ws + 4194304);             //  6.29 MB  [3072][1024]
    unsigned short* WoT   = (unsigned short*)(ws + 10485760);            //  2.10 MB  [1024][1024]
    unsigned short* qkv   = (unsigned short*)(ws + 12582912);            // 12.58 MB  [2048][3072]
    unsigned short* attnO = (unsigned short*)(ws + 25165824);            //  4.19 MB  [2048][1024]

    convert_x<<<2048, 256, 0, stream>>>(x, Xb);
    transpose_w<<<dim3(8, 16),  256, 0, stream>>>(wq_sem, WcatT,               512);
    transpose_w<<<dim3(8, 16),  256, 0, stream>>>(wk_sem, WcatT + 512  * 1024, 512);
    transpose_w<<<dim3(8, 16),  256, 0, stream>>>(wq_geo, WcatT + 1024 * 1024, 512);
    transpose_w<<<dim3(8, 16),  256, 0, stream>>>(wk_geo, WcatT + 1536 * 1024, 512);
    transpose_w<<<dim3(16, 16), 256, 0, stream>>>(wv,     WcatT + 2048 * 1024, 1024);
    transpose_w<<<dim3(16, 16), 256, 0, stream>>>(wo,     WoT,                 1024);

    gemm_proj<<<dim3(QKV_W / 128, TSEQ / 128), 256, 0, stream>>>(Xb, WcatT, qkv);
    rope_kernel<<<(TSEQ * 512) / 256, 256, 0, stream>>>((bf16*)qkv);
    attn_mfma<<<dim3(TSEQ / 64, NHEAD), 256, 0, stream>>>(qkv, ksn, kgn, vn, attnO);
    gemm_out<<<dim3(DMODEL / 128, TSEQ / 128), 256, 0, stream>>>(attnO, WoT, out);
}

// Round 4
// 163.390 us; speedup vs baseline: 4.7982x; 1.0611x over previous
//
#include <hip/hip_runtime.h>
#include <hip/hip_bf16.h>

typedef __hip_bfloat16 bf16;
typedef __attribute__((ext_vector_type(8))) short bf16x8;   // 8 bf16 = 4 VGPR (MFMA A/B frag)
typedef __attribute__((ext_vector_type(4))) float f32x4;    // MFMA C/D frag

#define TSEQ   2048
#define DMODEL 1024
#define NHEAD  16
#define QKV_W  3072   // [0,512) qs | [512,1024) ks | [1024,1536) qg | [1536,2048) kg | [2048,3072) v
#define KST    2112   // padded key count (2049 real, zero-padded), 33*64
#define SCALE  0.17677669529663687f  // 1/sqrt(32) == sem_scale == geo_scale

__device__ __forceinline__ unsigned short f2bf(float f) {
    union { bf16 h; unsigned short u; } x;
    x.h = __float2bfloat16(f);
    return x.u;
}

__device__ __forceinline__ void gload_lds16(const void* g, void* l) {
    __builtin_amdgcn_global_load_lds(
        (const __attribute__((address_space(1))) void*)g,
        (__attribute__((address_space(3))) void*)l, 16, 0, 0);
}

// ---------------------------------------------------------------------------
// Prep: f32 -> bf16 convert of X
// ---------------------------------------------------------------------------
__global__ __launch_bounds__(256) void convert_x(const float* __restrict__ X,
                                                 unsigned short* __restrict__ Xb)
{
    int i = (blockIdx.x * 256 + threadIdx.x) * 4;
    float4 v = *(const float4*)(X + i);
    ushort4 o;
    o.x = f2bf(v.x); o.y = f2bf(v.y); o.z = f2bf(v.z); o.w = f2bf(v.w);
    *(ushort4*)(Xb + i) = o;
}

// ---------------------------------------------------------------------------
// Prep: transpose + convert  dst[C][1024] (bf16) = src[1024][C] (f32)^T
// ---------------------------------------------------------------------------
__global__ __launch_bounds__(256) void transpose_w(const float* __restrict__ src,
                                                   unsigned short* __restrict__ dst,
                                                   int C)
{
    __shared__ float T[64][65];
    const int c0 = blockIdx.x * 64, r0 = blockIdx.y * 64;
    const int tid = threadIdx.x;
    #pragma unroll
    for (int i = 0; i < 16; ++i) {
        int idx = tid + 256 * i;
        int r = idx >> 6, c = idx & 63;
        T[r][c] = src[(size_t)(r0 + r) * C + c0 + c];
    }
    __syncthreads();
    #pragma unroll
    for (int i = 0; i < 16; ++i) {
        int idx = tid + 256 * i;
        int cc = idx >> 6, rr = idx & 63;
        dst[(size_t)(c0 + cc) * 1024 + r0 + rr] = f2bf(T[rr][cc]);
    }
}

// ---------------------------------------------------------------------------
// Prep: Kc[h][fk][64] combined sem|geo K rows. fk=0 null, [1,2048] real
// (post-RoPE), [2049,2112) zero. Contiguous 128B rows per key.
// ---------------------------------------------------------------------------
__global__ __launch_bounds__(256) void prep_k(
    const unsigned short* __restrict__ qkv,
    const float* __restrict__ ksn, const float* __restrict__ kgn,
    unsigned short* __restrict__ Kc)
{
    const int h = blockIdx.y, ft = blockIdx.x;   // ft < 33
    const int tid = threadIdx.x;
    const int d = tid & 63;
    #pragma unroll
    for (int i = 0; i < 16; ++i) {
        int fk = ft * 64 + i * 4 + (tid >> 6);
        unsigned short u;
        if (fk == 0)
            u = f2bf(d < 32 ? ksn[h * 32 + d] : kgn[h * 32 + d - 32]);
        else if (fk <= TSEQ) {
            int col = (d < 32) ? (512 + h * 32 + d) : (1536 + h * 32 + d - 32);
            u = qkv[(size_t)(fk - 1) * QKV_W + col];
        } else u = 0;
        Kc[((size_t)h * KST + fk) * 64 + d] = u;
    }
}

// ---------------------------------------------------------------------------
// Prep: Vg[h][dv][fk] = V^T per head, fk=0 null, zero-padded to KST.
// ---------------------------------------------------------------------------
__global__ __launch_bounds__(256) void prep_v(
    const unsigned short* __restrict__ qkv, const float* __restrict__ vn,
    unsigned short* __restrict__ Vg)
{
    __shared__ unsigned short T[64][65];
    const int h = blockIdx.y, ft = blockIdx.x;   // ft < 33
    const int tid = threadIdx.x;
    #pragma unroll
    for (int i = 0; i < 16; ++i) {
        int idx = tid + 256 * i;
        int fkl = idx >> 6, dv = idx & 63;
        int fk = ft * 64 + fkl;
        unsigned short u;
        if (fk == 0)           u = f2bf(vn[h * 64 + dv]);
        else if (fk <= TSEQ)   u = qkv[(size_t)(fk - 1) * QKV_W + 2048 + h * 64 + dv];
        else                   u = 0;
        T[fkl][dv] = u;
    }
    __syncthreads();
    #pragma unroll
    for (int i = 0; i < 16; ++i) {
        int idx = tid + 256 * i;
        int dv = idx >> 6, fkl = idx & 63;
        Vg[((size_t)h * 64 + dv) * KST + ft * 64 + fkl] = T[fkl][dv];
    }
}

// ---------------------------------------------------------------------------
// MFMA GEMM (m97 structure): 128x128 tile, BK=32, 4 waves, 4x4 16x16x32 frags.
// ---------------------------------------------------------------------------
__global__ __launch_bounds__(256) void gemm_proj(const unsigned short* __restrict__ A,
                                                 const unsigned short* __restrict__ Bt,
                                                 unsigned short* __restrict__ C)
{
    __shared__ __align__(16) unsigned short Abuf[128 * 32];
    __shared__ __align__(16) unsigned short Bbuf[128 * 32];
    const int n0 = blockIdx.x * 128, m0 = blockIdx.y * 128;
    const int tid = threadIdx.x, l = tid & 63, wv = tid >> 6;
    const int wr = wv >> 1, wc = wv & 1;
    const int lr = l & 15, kf = (l >> 4) * 8;

    f32x4 acc[4][4];
    #pragma unroll
    for (int i = 0; i < 4; ++i)
        #pragma unroll
        for (int j = 0; j < 4; ++j) acc[i][j] = (f32x4){0.f, 0.f, 0.f, 0.f};

    for (int k0 = 0; k0 < 1024; k0 += 32) {
        #pragma unroll
        for (int it = 0; it < 2; ++it) {
            int c = it * 256 + wv * 64 + l;
            int row = c >> 2, seg = c & 3;
            gload_lds16(A  + (size_t)(m0 + row) * 1024 + k0 + seg * 8,
                        &Abuf[(it * 256 + wv * 64) * 8]);
            gload_lds16(Bt + (size_t)(n0 + row) * 1024 + k0 + seg * 8,
                        &Bbuf[(it * 256 + wv * 64) * 8]);
        }
        __syncthreads();
        bf16x8 af[4], bfv[4];
        #pragma unroll
        for (int mf = 0; mf < 4; ++mf)
            af[mf] = *(const bf16x8*)&Abuf[(wr * 64 + mf * 16 + lr) * 32 + kf];
        #pragma unroll
        for (int nf = 0; nf < 4; ++nf)
            bfv[nf] = *(const bf16x8*)&Bbuf[(wc * 64 + nf * 16 + lr) * 32 + kf];
        #pragma unroll
        for (int mf = 0; mf < 4; ++mf)
            #pragma unroll
            for (int nf = 0; nf < 4; ++nf)
                acc[mf][nf] = __builtin_amdgcn_mfma_f32_16x16x32_bf16(
                    af[mf], bfv[nf], acc[mf][nf], 0, 0, 0);
        __syncthreads();
    }
    #pragma unroll
    for (int mf = 0; mf < 4; ++mf)
        #pragma unroll
        for (int nf = 0; nf < 4; ++nf)
            #pragma unroll
            for (int reg = 0; reg < 4; ++reg) {
                int row = m0 + wr * 64 + mf * 16 + (l >> 4) * 4 + reg;
                int col = n0 + wc * 64 + nf * 16 + lr;
                C[(size_t)row * QKV_W + col] = f2bf(acc[mf][nf][reg]);
            }
}

__global__ __launch_bounds__(256) void gemm_out(const unsigned short* __restrict__ A,
                                                const unsigned short* __restrict__ Bt,
                                                float* __restrict__ C)
{
    __shared__ __align__(16) unsigned short Abuf[128 * 32];
    __shared__ __align__(16) unsigned short Bbuf[128 * 32];
    const int n0 = blockIdx.x * 128, m0 = blockIdx.y * 128;
    const int tid = threadIdx.x, l = tid & 63, wv = tid >> 6;
    const int wr = wv >> 1, wc = wv & 1;
    const int lr = l & 15, kf = (l >> 4) * 8;

    f32x4 acc[4][4];
    #pragma unroll
    for (int i = 0; i < 4; ++i)
        #pragma unroll
        for (int j = 0; j < 4; ++j) acc[i][j] = (f32x4){0.f, 0.f, 0.f, 0.f};

    for (int k0 = 0; k0 < 1024; k0 += 32) {
        #pragma unroll
        for (int it = 0; it < 2; ++it) {
            int c = it * 256 + wv * 64 + l;
            int row = c >> 2, seg = c & 3;
            gload_lds16(A  + (size_t)(m0 + row) * 1024 + k0 + seg * 8,
                        &Abuf[(it * 256 + wv * 64) * 8]);
            gload_lds16(Bt + (size_t)(n0 + row) * 1024 + k0 + seg * 8,
                        &Bbuf[(it * 256 + wv * 64) * 8]);
        }
        __syncthreads();
        bf16x8 af[4], bfv[4];
        #pragma unroll
        for (int mf = 0; mf < 4; ++mf)
            af[mf] = *(const bf16x8*)&Abuf[(wr * 64 + mf * 16 + lr) * 32 + kf];
        #pragma unroll
        for (int nf = 0; nf < 4; ++nf)
            bfv[nf] = *(const bf16x8*)&Bbuf[(wc * 64 + nf * 16 + lr) * 32 + kf];
        #pragma unroll
        for (int mf = 0; mf < 4; ++mf)
            #pragma unroll
            for (int nf = 0; nf < 4; ++nf)
                acc[mf][nf] = __builtin_amdgcn_mfma_f32_16x16x32_bf16(
                    af[mf], bfv[nf], acc[mf][nf], 0, 0, 0);
        __syncthreads();
    }
    #pragma unroll
    for (int mf = 0; mf < 4; ++mf)
        #pragma unroll
        for (int nf = 0; nf < 4; ++nf)
            #pragma unroll
            for (int reg = 0; reg < 4; ++reg) {
                int row = m0 + wr * 64 + mf * 16 + (l >> 4) * 4 + reg;
                int col = n0 + wc * 64 + nf * 16 + lr;
                C[(size_t)row * DMODEL + col] = acc[mf][nf][reg];
            }
}

// ---------------------------------------------------------------------------
// RoPE in-place on qg / kg columns of the bf16 qkv buffer.
// ---------------------------------------------------------------------------
__global__ __launch_bounds__(256) void rope_kernel(bf16* __restrict__ qkv)
{
    int idx = blockIdx.x * 256 + threadIdx.x;   // < 2048*512
    int t     = idx >> 9;
    int rem   = idx & 511;
    int which = rem >> 8;
    int h     = (rem >> 4) & 15;
    int i     = rem & 15;
    bf16* base = qkv + (size_t)t * QKV_W + 1024 + which * 512 + h * 32;
    float inv = __expf(-((float)(2 * i) * (1.0f / 32.0f)) * 9.210340371976184f);
    float ang = (float)t * inv;
    float c = cosf(ang), s = sinf(ang);
    float x1 = __bfloat162float(base[i]);
    float x2 = __bfloat162float(base[i + 16]);
    base[i]      = __float2bfloat16(x1 * c - x2 * s);
    base[i + 16] = __float2bfloat16(x2 * c + x1 * s);
}

// ---------------------------------------------------------------------------
// MFMA flash attention, double-buffered global_load_lds staging.
// Block = 1 head x 64 queries, 4 waves x 16 rows, KVBLK=64.
// K/V tiles land swizzled in LDS via pre-swizzled SOURCE addresses (rule #21):
// LDS[row][chunk j] holds source chunk j^(row&7) (16B granules).
// ---------------------------------------------------------------------------
__global__ __launch_bounds__(256) void attn_mfma(
    const unsigned short* __restrict__ qkv,
    const unsigned short* __restrict__ Kc,
    const unsigned short* __restrict__ Vg,
    unsigned short* __restrict__ attnO)
{
    __shared__ __align__(16) unsigned short KsL[2][64 * 64];
    __shared__ __align__(16) unsigned short VsL[2][64 * 64];
    __shared__ __align__(16) unsigned short Ps[64 * 64];

    const int h  = blockIdx.y;
    const int qb = gridDim.x - 1 - blockIdx.x;   // heavy (high-q) blocks first
    const int q0 = qb * 64;
    const int tid = threadIdx.x, l = tid & 63, w = tid >> 6;
    const int lr = l & 15, lg = l >> 4;

    // Q fragments in registers (A-frag: row=lane&15, k=(lane>>4)*8)
    const int qrow = q0 + w * 16 + lr;
    const int d0 = lg * 8;
    bf16x8 qa0 = *(const bf16x8*)&qkv[(size_t)qrow * QKV_W + h * 32 + d0];
    bf16x8 qa1 = *(const bf16x8*)&qkv[(size_t)qrow * QKV_W + 1024 + h * 32 + d0];

    // staging: granule g = (w*2+i)*64 + l; row = g>>3, chunk j = l&7.
    // source chunk = j ^ (row&7) = (l&7) ^ ((l>>3)&7)  (lane-constant)
    const int sc8 = (((l & 7) ^ ((l >> 3) & 7))) * 8;
    const int r0s = (w * 2 + 0) * 8 + (l >> 3);
    const int r1s = (w * 2 + 1) * 8 + (l >> 3);
    const unsigned short* Kh = Kc + (((size_t)h * KST) << 6);
    const unsigned short* Vh = Vg + (size_t)h * 64 * KST;

#define STAGE_KV(bufi, fk0_) do {                                              \
        gload_lds16(Kh + (((size_t)((fk0_) + r0s)) << 6) + sc8,                \
                    &KsL[bufi][(w * 2 + 0) * 512]);                            \
        gload_lds16(Kh + (((size_t)((fk0_) + r1s)) << 6) + sc8,                \
                    &KsL[bufi][(w * 2 + 1) * 512]);                            \
        gload_lds16(Vh + (size_t)r0s * KST + (fk0_) + sc8,                     \
                    &VsL[bufi][(w * 2 + 0) * 512]);                            \
        gload_lds16(Vh + (size_t)r1s * KST + (fk0_) + sc8,                     \
                    &VsL[bufi][(w * 2 + 1) * 512]);                            \
    } while (0)

    f32x4 o[4];
    #pragma unroll
    for (int i = 0; i < 4; ++i) o[i] = (f32x4){0.f, 0.f, 0.f, 0.f};
    float m[4]  = {-1e30f, -1e30f, -1e30f, -1e30f};
    float ll[4] = {0.f, 0.f, 0.f, 0.f};

    const int nkb = qb + 2;
    int buf = 0;
    STAGE_KV(0, 0);
    asm volatile("s_waitcnt vmcnt(0)" ::: "memory");
    __builtin_amdgcn_s_barrier();

    for (int kb = 0; kb < nkb; ++kb) {
        const int fk0 = kb * 64;
        if (kb + 1 < nkb) STAGE_KV(buf ^ 1, fk0 + 64);   // prefetch next tile

        const unsigned short* Ksb = &KsL[buf][0];
        const unsigned short* Vsb = &VsL[buf][0];

        // ---- QK^T
        f32x4 sa[4];
        #pragma unroll
        for (int i = 0; i < 4; ++i) sa[i] = (f32x4){0.f, 0.f, 0.f, 0.f};
        __builtin_amdgcn_s_setprio(1);
        #pragma unroll
        for (int ks = 0; ks < 2; ++ks) {
            int dd = lg * 8 + ks * 32;
            bf16x8 qa = ks ? qa1 : qa0;
            #pragma unroll
            for (int nf = 0; nf < 4; ++nf) {
                int kkc = nf * 16 + lr;
                bf16x8 kbf = *(const bf16x8*)&Ksb[kkc * 64 + (dd ^ ((kkc & 7) << 3))];
                sa[nf] = __builtin_amdgcn_mfma_f32_16x16x32_bf16(qa, kbf, sa[nf], 0, 0, 0);
            }
        }
        __builtin_amdgcn_s_setprio(0);

        // ---- mask + scale + online softmax (in-register, rows span 16 lanes)
        float sv[4][4];
        float mt[4] = {-1e30f, -1e30f, -1e30f, -1e30f};
        #pragma unroll
        for (int nf = 0; nf < 4; ++nf)
            #pragma unroll
            for (int reg = 0; reg < 4; ++reg) {
                int q  = q0 + w * 16 + lg * 4 + reg;
                int fk = fk0 + nf * 16 + lr;
                float val = (fk <= q + 1) ? sa[nf][reg] * SCALE : -1e9f;
                sv[nf][reg] = val;
                mt[reg] = fmaxf(mt[reg], val);
            }
        #pragma unroll
        for (int reg = 0; reg < 4; ++reg) {
            #pragma unroll
            for (int off = 1; off < 16; off <<= 1)
                mt[reg] = fmaxf(mt[reg], __shfl_xor(mt[reg], off, 64));
        }
        float alpha[4], rs[4];
        #pragma unroll
        for (int reg = 0; reg < 4; ++reg) {
            float mn = fmaxf(m[reg], mt[reg]);
            alpha[reg] = __expf(m[reg] - mn);
            m[reg] = mn;
        }
        #pragma unroll
        for (int nf = 0; nf < 4; ++nf)
            #pragma unroll
            for (int reg = 0; reg < 4; ++reg)
                sv[nf][reg] = __expf(sv[nf][reg] - m[reg]);
        #pragma unroll
        for (int reg = 0; reg < 4; ++reg) {
            rs[reg] = sv[0][reg] + sv[1][reg] + sv[2][reg] + sv[3][reg];
            #pragma unroll
            for (int off = 1; off < 16; off <<= 1)
                rs[reg] += __shfl_xor(rs[reg], off, 64);
            ll[reg] = ll[reg] * alpha[reg] + rs[reg];
        }
        #pragma unroll
        for (int nf = 0; nf < 4; ++nf)
            #pragma unroll
            for (int reg = 0; reg < 4; ++reg)
                o[nf][reg] *= alpha[reg];

        // ---- P -> bf16 -> LDS (swizzled)
        #pragma unroll
        for (int nf = 0; nf < 4; ++nf)
            #pragma unroll
            for (int reg = 0; reg < 4; ++reg) {
                int r  = w * 16 + lg * 4 + reg;
                int kk = nf * 16 + lr;
                Ps[r * 64 + (kk ^ ((r & 7) << 3))] = f2bf(sv[nf][reg]);
            }
        // Ps visible to all waves; staging vmcnt stays outstanding across barrier
        asm volatile("s_waitcnt lgkmcnt(0)" ::: "memory");
        __builtin_amdgcn_s_barrier();

        // ---- PV: O += P @ V
        __builtin_amdgcn_s_setprio(1);
        #pragma unroll
        for (int ks = 0; ks < 2; ++ks) {
            int kk0 = lg * 8 + ks * 32;
            int pr  = w * 16 + lr;
            bf16x8 pa = *(const bf16x8*)&Ps[pr * 64 + (kk0 ^ ((pr & 7) << 3))];
            #pragma unroll
            for (int nf = 0; nf < 4; ++nf) {
                int dv = nf * 16 + lr;
                bf16x8 vb = *(const bf16x8*)&Vsb[dv * 64 + (kk0 ^ ((dv & 7) << 3))];
                o[nf] = __builtin_amdgcn_mfma_f32_16x16x32_bf16(pa, vb, o[nf], 0, 0, 0);
            }
        }
        __builtin_amdgcn_s_setprio(0);

        // next tile staged + everyone done with Ps/Vsb
        asm volatile("s_waitcnt vmcnt(0) lgkmcnt(0)" ::: "memory");
        __builtin_amdgcn_s_barrier();
        buf ^= 1;
    }
#undef STAGE_KV

    float inv[4];
    #pragma unroll
    for (int reg = 0; reg < 4; ++reg) inv[reg] = 1.0f / ll[reg];
    #pragma unroll
    for (int nf = 0; nf < 4; ++nf)
        #pragma unroll
        for (int reg = 0; reg < 4; ++reg) {
            int q = q0 + w * 16 + lg * 4 + reg;
            attnO[(size_t)q * DMODEL + h * 64 + nf * 16 + lr] = f2bf(o[nf][reg] * inv[reg]);
        }
}

// ---------------------------------------------------------------------------
extern "C" void kernel_launch(void* const* d_in, const int* in_sizes, int n_in,
                              void* d_out, int out_size, void* d_ws, size_t ws_size,
                              hipStream_t stream)
{
    const float* x      = (const float*)d_in[0];
    const float* wq_sem = (const float*)d_in[1];
    const float* wk_sem = (const float*)d_in[2];
    const float* wq_geo = (const float*)d_in[3];
    const float* wk_geo = (const float*)d_in[4];
    const float* wv     = (const float*)d_in[5];
    const float* wo     = (const float*)d_in[6];
    const float* ksn    = (const float*)d_in[7];
    const float* kgn    = (const float*)d_in[8];
    const float* vn     = (const float*)d_in[9];
    float* out = (float*)d_out;

    // Workspace regions (reuse, total 27.4 MB — under proven 29.4 MB bound):
    //  [0, 12.58M)        qkv [2048][3072] bf16
    //  [12.58M, 18.87M)   WcatT (6.29M)  -> later Vg [16][64][2112] (4.33M)
    //  [18.87M, 23.20M)   Kc [16][2112][64] (4.33M) -> later WoT (2.10M)
    //  [23.20M, 27.39M)   Xb (4.19M) -> later attnO (4.19M)
    char* ws = (char*)d_ws;
    unsigned short* qkv   = (unsigned short*)(ws);
    unsigned short* WcatT = (unsigned short*)(ws + 12582912);
    unsigned short* Vg    = (unsigned short*)(ws + 12582912);
    unsigned short* Kc    = (unsigned short*)(ws + 18874368);
    unsigned short* WoT   = (unsigned short*)(ws + 18874368);
    unsigned short* Xb    = (unsigned short*)(ws + 23199744);
    unsigned short* attnO = (unsigned short*)(ws + 23199744);

    convert_x<<<2048, 256, 0, stream>>>(x, Xb);
    transpose_w<<<dim3(8, 16),  256, 0, stream>>>(wq_sem, WcatT,               512);
    transpose_w<<<dim3(8, 16),  256, 0, stream>>>(wk_sem, WcatT + 512  * 1024, 512);
    transpose_w<<<dim3(8, 16),  256, 0, stream>>>(wq_geo, WcatT + 1024 * 1024, 512);
    transpose_w<<<dim3(8, 16),  256, 0, stream>>>(wk_geo, WcatT + 1536 * 1024, 512);
    transpose_w<<<dim3(16, 16), 256, 0, stream>>>(wv,     WcatT + 2048 * 1024, 1024);

    gemm_proj<<<dim3(QKV_W / 128, TSEQ / 128), 256, 0, stream>>>(Xb, WcatT, qkv);
    rope_kernel<<<(TSEQ * 512) / 256, 256, 0, stream>>>((bf16*)qkv);

    prep_k<<<dim3(33, 16), 256, 0, stream>>>(qkv, ksn, kgn, Kc);
    prep_v<<<dim3(33, 16), 256, 0, stream>>>(qkv, vn, Vg);

    attn_mfma<<<dim3(TSEQ / 64, NHEAD), 256, 0, stream>>>(qkv, Kc, Vg, attnO);

    transpose_w<<<dim3(16, 16), 256, 0, stream>>>(wo, WoT, 1024);
    gemm_out<<<dim3(DMODEL / 128, TSEQ / 128), 256, 0, stream>>>(attnO, WoT, out);
}

// Round 5
// 143.560 us; speedup vs baseline: 5.4610x; 1.1381x over previous
//
#include <hip/hip_runtime.h>
#include <hip/hip_bf16.h>

typedef __hip_bfloat16 bf16;
typedef __attribute__((ext_vector_type(8))) short bf16x8;   // 8 bf16 = 4 VGPR (MFMA A/B frag)
typedef __attribute__((ext_vector_type(4))) float f32x4;    // MFMA C/D frag

#define TSEQ   2048
#define DMODEL 1024
#define NHEAD  16
#define QKV_W  3072   // [0,512) qs | [512,1024) ks | [1024,1536) qg | [1536,2048) kg | [2048,3072) v
#define KST    2112   // padded key count (2049 real, zero-padded), 33*64
#define SCALE  0.17677669529663687f  // 1/sqrt(32) == sem_scale == geo_scale

__device__ __forceinline__ unsigned short f2bf(float f) {
    union { bf16 h; unsigned short u; } x;
    x.h = __float2bfloat16(f);
    return x.u;
}

__device__ __forceinline__ void gload_lds16(const void* g, void* l) {
    __builtin_amdgcn_global_load_lds(
        (const __attribute__((address_space(1))) void*)g,
        (__attribute__((address_space(3))) void*)l, 16, 0, 0);
}

// ---------------------------------------------------------------------------
// Prep: f32 -> bf16 convert of X
// ---------------------------------------------------------------------------
__global__ __launch_bounds__(256) void convert_x(const float* __restrict__ X,
                                                 unsigned short* __restrict__ Xb)
{
    int i = (blockIdx.x * 256 + threadIdx.x) * 4;
    float4 v = *(const float4*)(X + i);
    ushort4 o;
    o.x = f2bf(v.x); o.y = f2bf(v.y); o.z = f2bf(v.z); o.w = f2bf(v.w);
    *(ushort4*)(Xb + i) = o;
}

// ---------------------------------------------------------------------------
// Prep: transpose + convert  dst[C][1024] (bf16) = src[1024][C] (f32)^T
// ---------------------------------------------------------------------------
__global__ __launch_bounds__(256) void transpose_w(const float* __restrict__ src,
                                                   unsigned short* __restrict__ dst,
                                                   int C)
{
    __shared__ float T[64][65];
    const int c0 = blockIdx.x * 64, r0 = blockIdx.y * 64;
    const int tid = threadIdx.x;
    #pragma unroll
    for (int i = 0; i < 16; ++i) {
        int idx = tid + 256 * i;
        int r = idx >> 6, c = idx & 63;
        T[r][c] = src[(size_t)(r0 + r) * C + c0 + c];
    }
    __syncthreads();
    #pragma unroll
    for (int i = 0; i < 16; ++i) {
        int idx = tid + 256 * i;
        int cc = idx >> 6, rr = idx & 63;
        dst[(size_t)(c0 + cc) * 1024 + r0 + rr] = f2bf(T[rr][cc]);
    }
}

// ---------------------------------------------------------------------------
// Prep: Kc[h][fk][64] combined sem|geo K rows. fk=0 null, [1,2048] real
// (post-RoPE), [2049,2112) zero.
// ---------------------------------------------------------------------------
__global__ __launch_bounds__(256) void prep_k(
    const unsigned short* __restrict__ qkv,
    const float* __restrict__ ksn, const float* __restrict__ kgn,
    unsigned short* __restrict__ Kc)
{
    const int h = blockIdx.y, ft = blockIdx.x;   // ft < 33
    const int tid = threadIdx.x;
    const int d = tid & 63;
    #pragma unroll
    for (int i = 0; i < 16; ++i) {
        int fk = ft * 64 + i * 4 + (tid >> 6);
        unsigned short u;
        if (fk == 0)
            u = f2bf(d < 32 ? ksn[h * 32 + d] : kgn[h * 32 + d - 32]);
        else if (fk <= TSEQ) {
            int col = (d < 32) ? (512 + h * 32 + d) : (1536 + h * 32 + d - 32);
            u = qkv[(size_t)(fk - 1) * QKV_W + col];
        } else u = 0;
        Kc[((size_t)h * KST + fk) * 64 + d] = u;
    }
}

// ---------------------------------------------------------------------------
// Prep: Vg[h][dv][fk] = V^T per head, fk=0 null, zero-padded to KST.
// ---------------------------------------------------------------------------
__global__ __launch_bounds__(256) void prep_v(
    const unsigned short* __restrict__ qkv, const float* __restrict__ vn,
    unsigned short* __restrict__ Vg)
{
    __shared__ unsigned short T[64][65];
    const int h = blockIdx.y, ft = blockIdx.x;   // ft < 33
    const int tid = threadIdx.x;
    #pragma unroll
    for (int i = 0; i < 16; ++i) {
        int idx = tid + 256 * i;
        int fkl = idx >> 6, dv = idx & 63;
        int fk = ft * 64 + fkl;
        unsigned short u;
        if (fk == 0)           u = f2bf(vn[h * 64 + dv]);
        else if (fk <= TSEQ)   u = qkv[(size_t)(fk - 1) * QKV_W + 2048 + h * 64 + dv];
        else                   u = 0;
        T[fkl][dv] = u;
    }
    __syncthreads();
    #pragma unroll
    for (int i = 0; i < 16; ++i) {
        int idx = tid + 256 * i;
        int dv = idx >> 6, fkl = idx & 63;
        Vg[((size_t)h * 64 + dv) * KST + ft * 64 + fkl] = T[fkl][dv];
    }
}

// ---------------------------------------------------------------------------
// MFMA GEMM (m97 structure): 128x128 tile, BK=32, 4 waves, 4x4 16x16x32 frags.
// ---------------------------------------------------------------------------
__global__ __launch_bounds__(256) void gemm_proj(const unsigned short* __restrict__ A,
                                                 const unsigned short* __restrict__ Bt,
                                                 unsigned short* __restrict__ C)
{
    __shared__ __align__(16) unsigned short Abuf[128 * 32];
    __shared__ __align__(16) unsigned short Bbuf[128 * 32];
    const int n0 = blockIdx.x * 128, m0 = blockIdx.y * 128;
    const int tid = threadIdx.x, l = tid & 63, wv = tid >> 6;
    const int wr = wv >> 1, wc = wv & 1;
    const int lr = l & 15, kf = (l >> 4) * 8;

    f32x4 acc[4][4];
    #pragma unroll
    for (int i = 0; i < 4; ++i)
        #pragma unroll
        for (int j = 0; j < 4; ++j) acc[i][j] = (f32x4){0.f, 0.f, 0.f, 0.f};

    for (int k0 = 0; k0 < 1024; k0 += 32) {
        #pragma unroll
        for (int it = 0; it < 2; ++it) {
            int c = it * 256 + wv * 64 + l;
            int row = c >> 2, seg = c & 3;
            gload_lds16(A  + (size_t)(m0 + row) * 1024 + k0 + seg * 8,
                        &Abuf[(it * 256 + wv * 64) * 8]);
            gload_lds16(Bt + (size_t)(n0 + row) * 1024 + k0 + seg * 8,
                        &Bbuf[(it * 256 + wv * 64) * 8]);
        }
        __syncthreads();
        bf16x8 af[4], bfv[4];
        #pragma unroll
        for (int mf = 0; mf < 4; ++mf)
            af[mf] = *(const bf16x8*)&Abuf[(wr * 64 + mf * 16 + lr) * 32 + kf];
        #pragma unroll
        for (int nf = 0; nf < 4; ++nf)
            bfv[nf] = *(const bf16x8*)&Bbuf[(wc * 64 + nf * 16 + lr) * 32 + kf];
        #pragma unroll
        for (int mf = 0; mf < 4; ++mf)
            #pragma unroll
            for (int nf = 0; nf < 4; ++nf)
                acc[mf][nf] = __builtin_amdgcn_mfma_f32_16x16x32_bf16(
                    af[mf], bfv[nf], acc[mf][nf], 0, 0, 0);
        __syncthreads();
    }
    #pragma unroll
    for (int mf = 0; mf < 4; ++mf)
        #pragma unroll
        for (int nf = 0; nf < 4; ++nf)
            #pragma unroll
            for (int reg = 0; reg < 4; ++reg) {
                int row = m0 + wr * 64 + mf * 16 + (l >> 4) * 4 + reg;
                int col = n0 + wc * 64 + nf * 16 + lr;
                C[(size_t)row * QKV_W + col] = f2bf(acc[mf][nf][reg]);
            }
}

__global__ __launch_bounds__(256) void gemm_out(const unsigned short* __restrict__ A,
                                                const unsigned short* __restrict__ Bt,
                                                float* __restrict__ C)
{
    __shared__ __align__(16) unsigned short Abuf[128 * 32];
    __shared__ __align__(16) unsigned short Bbuf[128 * 32];
    const int n0 = blockIdx.x * 128, m0 = blockIdx.y * 128;
    const int tid = threadIdx.x, l = tid & 63, wv = tid >> 6;
    const int wr = wv >> 1, wc = wv & 1;
    const int lr = l & 15, kf = (l >> 4) * 8;

    f32x4 acc[4][4];
    #pragma unroll
    for (int i = 0; i < 4; ++i)
        #pragma unroll
        for (int j = 0; j < 4; ++j) acc[i][j] = (f32x4){0.f, 0.f, 0.f, 0.f};

    for (int k0 = 0; k0 < 1024; k0 += 32) {
        #pragma unroll
        for (int it = 0; it < 2; ++it) {
            int c = it * 256 + wv * 64 + l;
            int row = c >> 2, seg = c & 3;
            gload_lds16(A  + (size_t)(m0 + row) * 1024 + k0 + seg * 8,
                        &Abuf[(it * 256 + wv * 64) * 8]);
            gload_lds16(Bt + (size_t)(n0 + row) * 1024 + k0 + seg * 8,
                        &Bbuf[(it * 256 + wv * 64) * 8]);
        }
        __syncthreads();
        bf16x8 af[4], bfv[4];
        #pragma unroll
        for (int mf = 0; mf < 4; ++mf)
            af[mf] = *(const bf16x8*)&Abuf[(wr * 64 + mf * 16 + lr) * 32 + kf];
        #pragma unroll
        for (int nf = 0; nf < 4; ++nf)
            bfv[nf] = *(const bf16x8*)&Bbuf[(wc * 64 + nf * 16 + lr) * 32 + kf];
        #pragma unroll
        for (int mf = 0; mf < 4; ++mf)
            #pragma unroll
            for (int nf = 0; nf < 4; ++nf)
                acc[mf][nf] = __builtin_amdgcn_mfma_f32_16x16x32_bf16(
                    af[mf], bfv[nf], acc[mf][nf], 0, 0, 0);
        __syncthreads();
    }
    #pragma unroll
    for (int mf = 0; mf < 4; ++mf)
        #pragma unroll
        for (int nf = 0; nf < 4; ++nf)
            #pragma unroll
            for (int reg = 0; reg < 4; ++reg) {
                int row = m0 + wr * 64 + mf * 16 + (l >> 4) * 4 + reg;
                int col = n0 + wc * 64 + nf * 16 + lr;
                C[(size_t)row * DMODEL + col] = acc[mf][nf][reg];
            }
}

// ---------------------------------------------------------------------------
// RoPE in-place on qg / kg columns of the bf16 qkv buffer.
// ---------------------------------------------------------------------------
__global__ __launch_bounds__(256) void rope_kernel(bf16* __restrict__ qkv)
{
    int idx = blockIdx.x * 256 + threadIdx.x;   // < 2048*512
    int t     = idx >> 9;
    int rem   = idx & 511;
    int which = rem >> 8;
    int h     = (rem >> 4) & 15;
    int i     = rem & 15;
    bf16* base = qkv + (size_t)t * QKV_W + 1024 + which * 512 + h * 32;
    float inv = __expf(-((float)(2 * i) * (1.0f / 32.0f)) * 9.210340371976184f);
    float ang = (float)t * inv;
    float c = cosf(ang), s = sinf(ang);
    float x1 = __bfloat162float(base[i]);
    float x2 = __bfloat162float(base[i + 16]);
    base[i]      = __float2bfloat16(x1 * c - x2 * s);
    base[i + 16] = __float2bfloat16(x2 * c + x1 * s);
}

// ---------------------------------------------------------------------------
// MFMA flash attention with 2-way split-K for heavy blocks.
// blockIdx.x in [0,48): i<32 -> split item (qb=31-(i>>1), part=i&1, halves of
// the kv range); i>=32 -> single item (qb=47-i, full range). Heavy first.
// 4 waves x 16 q rows; KVBLK=64; double-buffered global_load_lds staging with
// swizzle folded into per-lane SOURCE address. ONE barrier per iteration
// (Ps is wave-local: written and read by the same wave's rows).
// ---------------------------------------------------------------------------
__global__ __launch_bounds__(256) void attn_mfma(
    const unsigned short* __restrict__ qkv,
    const unsigned short* __restrict__ Kc,
    const unsigned short* __restrict__ Vg,
    unsigned short* __restrict__ attnO,
    unsigned short* __restrict__ Opart,
    float2* __restrict__ ml)
{
    __shared__ __align__(16) unsigned short KsL[2][64 * 64];
    __shared__ __align__(16) unsigned short VsL[2][64 * 64];
    __shared__ __align__(16) unsigned short Ps[64 * 64];

    const int h = blockIdx.y;
    int qb, t0, t1, part;
    bool split;
    {
        int i = blockIdx.x;
        if (i < 32) {
            split = true; qb = 31 - (i >> 1); part = i & 1;
            int nk = qb + 2, half = nk >> 1;
            t0 = part ? half : 0;
            t1 = part ? nk : half;
        } else {
            split = false; qb = 47 - i; part = 0;
            t0 = 0; t1 = qb + 2;
        }
    }
    const int q0 = qb * 64;
    const int tid = threadIdx.x, l = tid & 63, w = tid >> 6;
    const int lr = l & 15, lg = l >> 4;

    // Q fragments in registers (A-frag: row=lane&15, k=(lane>>4)*8)
    const int qrow = q0 + w * 16 + lr;
    const int d0 = lg * 8;
    bf16x8 qa0 = *(const bf16x8*)&qkv[(size_t)qrow * QKV_W + h * 32 + d0];
    bf16x8 qa1 = *(const bf16x8*)&qkv[(size_t)qrow * QKV_W + 1024 + h * 32 + d0];

    // staging: granule g = (w*2+i)*64 + l; row = g>>3, chunk j = l&7.
    // source chunk = j ^ (row&7) = (l&7) ^ ((l>>3)&7)  (lane-constant)
    const int sc8 = (((l & 7) ^ ((l >> 3) & 7))) * 8;
    const int r0s = (w * 2 + 0) * 8 + (l >> 3);
    const int r1s = (w * 2 + 1) * 8 + (l >> 3);
    const unsigned short* Kh = Kc + (((size_t)h * KST) << 6);
    const unsigned short* Vh = Vg + (size_t)h * 64 * KST;

#define STAGE_KV(bufi, fk0_) do {                                              \
        gload_lds16(Kh + (((size_t)((fk0_) + r0s)) << 6) + sc8,                \
                    &KsL[bufi][(w * 2 + 0) * 512]);                            \
        gload_lds16(Kh + (((size_t)((fk0_) + r1s)) << 6) + sc8,                \
                    &KsL[bufi][(w * 2 + 1) * 512]);                            \
        gload_lds16(Vh + (size_t)r0s * KST + (fk0_) + sc8,                     \
                    &VsL[bufi][(w * 2 + 0) * 512]);                            \
        gload_lds16(Vh + (size_t)r1s * KST + (fk0_) + sc8,                     \
                    &VsL[bufi][(w * 2 + 1) * 512]);                            \
    } while (0)

    f32x4 o[4];
    #pragma unroll
    for (int i = 0; i < 4; ++i) o[i] = (f32x4){0.f, 0.f, 0.f, 0.f};
    float m[4]  = {-1e30f, -1e30f, -1e30f, -1e30f};
    float ll[4] = {0.f, 0.f, 0.f, 0.f};

    int buf = 0;
    STAGE_KV(0, t0 * 64);
    asm volatile("s_waitcnt vmcnt(0)" ::: "memory");
    __builtin_amdgcn_s_barrier();

    for (int kb = t0; kb < t1; ++kb) {
        const int fk0 = kb * 64;
        if (kb + 1 < t1) STAGE_KV(buf ^ 1, fk0 + 64);   // prefetch next tile

        const unsigned short* Ksb = &KsL[buf][0];
        const unsigned short* Vsb = &VsL[buf][0];

        // ---- QK^T
        f32x4 sa[4];
        #pragma unroll
        for (int i = 0; i < 4; ++i) sa[i] = (f32x4){0.f, 0.f, 0.f, 0.f};
        __builtin_amdgcn_s_setprio(1);
        #pragma unroll
        for (int ks = 0; ks < 2; ++ks) {
            int dd = lg * 8 + ks * 32;
            bf16x8 qa = ks ? qa1 : qa0;
            #pragma unroll
            for (int nf = 0; nf < 4; ++nf) {
                int kkc = nf * 16 + lr;
                bf16x8 kbf = *(const bf16x8*)&Ksb[kkc * 64 + (dd ^ ((kkc & 7) << 3))];
                sa[nf] = __builtin_amdgcn_mfma_f32_16x16x32_bf16(qa, kbf, sa[nf], 0, 0, 0);
            }
        }
        __builtin_amdgcn_s_setprio(0);

        // ---- mask + scale + online softmax (in-register, rows span 16 lanes)
        float sv[4][4];
        float mt[4] = {-1e30f, -1e30f, -1e30f, -1e30f};
        #pragma unroll
        for (int nf = 0; nf < 4; ++nf)
            #pragma unroll
            for (int reg = 0; reg < 4; ++reg) {
                int q  = q0 + w * 16 + lg * 4 + reg;
                int fk = fk0 + nf * 16 + lr;
                float val = (fk <= q + 1) ? sa[nf][reg] * SCALE : -1e9f;
                sv[nf][reg] = val;
                mt[reg] = fmaxf(mt[reg], val);
            }
        #pragma unroll
        for (int reg = 0; reg < 4; ++reg) {
            #pragma unroll
            for (int off = 1; off < 16; off <<= 1)
                mt[reg] = fmaxf(mt[reg], __shfl_xor(mt[reg], off, 64));
        }
        float alpha[4], rs[4];
        #pragma unroll
        for (int reg = 0; reg < 4; ++reg) {
            float mn = fmaxf(m[reg], mt[reg]);
            alpha[reg] = __expf(m[reg] - mn);
            m[reg] = mn;
        }
        #pragma unroll
        for (int nf = 0; nf < 4; ++nf)
            #pragma unroll
            for (int reg = 0; reg < 4; ++reg)
                sv[nf][reg] = __expf(sv[nf][reg] - m[reg]);
        #pragma unroll
        for (int reg = 0; reg < 4; ++reg) {
            rs[reg] = sv[0][reg] + sv[1][reg] + sv[2][reg] + sv[3][reg];
            #pragma unroll
            for (int off = 1; off < 16; off <<= 1)
                rs[reg] += __shfl_xor(rs[reg], off, 64);
            ll[reg] = ll[reg] * alpha[reg] + rs[reg];
        }
        #pragma unroll
        for (int nf = 0; nf < 4; ++nf)
            #pragma unroll
            for (int reg = 0; reg < 4; ++reg)
                o[nf][reg] *= alpha[reg];

        // ---- P -> bf16 -> LDS (swizzled, wave-local rows: no barrier needed)
        #pragma unroll
        for (int nf = 0; nf < 4; ++nf)
            #pragma unroll
            for (int reg = 0; reg < 4; ++reg) {
                int r  = w * 16 + lg * 4 + reg;
                int kk = nf * 16 + lr;
                Ps[r * 64 + (kk ^ ((r & 7) << 3))] = f2bf(sv[nf][reg]);
            }

        // ---- PV: O += P @ V  (compiler inserts lgkmcnt for Ps dependency)
        __builtin_amdgcn_s_setprio(1);
        #pragma unroll
        for (int ks = 0; ks < 2; ++ks) {
            int kk0 = lg * 8 + ks * 32;
            int pr  = w * 16 + lr;
            bf16x8 pa = *(const bf16x8*)&Ps[pr * 64 + (kk0 ^ ((pr & 7) << 3))];
            #pragma unroll
            for (int nf = 0; nf < 4; ++nf) {
                int dv = nf * 16 + lr;
                bf16x8 vb = *(const bf16x8*)&Vsb[dv * 64 + (kk0 ^ ((dv & 7) << 3))];
                o[nf] = __builtin_amdgcn_mfma_f32_16x16x32_bf16(pa, vb, o[nf], 0, 0, 0);
            }
        }
        __builtin_amdgcn_s_setprio(0);

        // next tile staged + all waves done reading this buf
        asm volatile("s_waitcnt vmcnt(0)" ::: "memory");
        __builtin_amdgcn_s_barrier();
        buf ^= 1;
    }
#undef STAGE_KV

    float inv[4];
    #pragma unroll
    for (int reg = 0; reg < 4; ++reg) inv[reg] = 1.0f / ll[reg];

    if (!split) {
        #pragma unroll
        for (int nf = 0; nf < 4; ++nf)
            #pragma unroll
            for (int reg = 0; reg < 4; ++reg) {
                int q = q0 + w * 16 + lg * 4 + reg;
                attnO[(size_t)q * DMODEL + h * 64 + nf * 16 + lr] =
                    f2bf(o[nf][reg] * inv[reg]);
            }
    } else {
        const int sidx = (h * 16 + (qb - 16)) * 2 + part;
        unsigned short* Od = Opart + (size_t)sidx * 4096;
        #pragma unroll
        for (int nf = 0; nf < 4; ++nf)
            #pragma unroll
            for (int reg = 0; reg < 4; ++reg) {
                int r = w * 16 + lg * 4 + reg;
                Od[r * 64 + nf * 16 + lr] = f2bf(o[nf][reg] * inv[reg]);
            }
        if (lr == 0) {
            #pragma unroll
            for (int reg = 0; reg < 4; ++reg) {
                int r = w * 16 + lg * 4 + reg;
                ml[sidx * 64 + r] = make_float2(m[reg], ll[reg]);
            }
        }
    }
}

// ---------------------------------------------------------------------------
// Combine split-K partials for qb in [16,32).
// ---------------------------------------------------------------------------
__global__ __launch_bounds__(256) void combine_split(
    const unsigned short* __restrict__ Opart,
    const float2* __restrict__ ml,
    unsigned short* __restrict__ attnO)
{
    const int h = blockIdx.x >> 4, qs = blockIdx.x & 15;
    const int qb = 16 + qs;
    const int base = (h * 16 + qs) * 2;
    const unsigned short* O0 = Opart + (size_t)base * 4096;
    const unsigned short* O1 = O0 + 4096;
    const float2* ml0 = ml + base * 64;
    const float2* ml1 = ml0 + 64;
    const int t = threadIdx.x;
    const int dv = t & 63, rg = t >> 6;
    #pragma unroll
    for (int i = 0; i < 16; ++i) {
        int r = rg + i * 4;
        float2 a = ml0[r], b = ml1[r];
        float mm = fmaxf(a.x, b.x);
        float w0 = a.y * __expf(a.x - mm);
        float w1 = b.y * __expf(b.x - mm);
        float inv = 1.0f / (w0 + w1);
        float o0 = __bfloat162float(*(const bf16*)&O0[r * 64 + dv]);
        float o1 = __bfloat162float(*(const bf16*)&O1[r * 64 + dv]);
        int q = qb * 64 + r;
        attnO[(size_t)q * DMODEL + h * 64 + dv] = f2bf((w0 * o0 + w1 * o1) * inv);
    }
}

// ---------------------------------------------------------------------------
extern "C" void kernel_launch(void* const* d_in, const int* in_sizes, int n_in,
                              void* d_out, int out_size, void* d_ws, size_t ws_size,
                              hipStream_t stream)
{
    const float* x      = (const float*)d_in[0];
    const float* wq_sem = (const float*)d_in[1];
    const float* wk_sem = (const float*)d_in[2];
    const float* wq_geo = (const float*)d_in[3];
    const float* wk_geo = (const float*)d_in[4];
    const float* wv     = (const float*)d_in[5];
    const float* wo     = (const float*)d_in[6];
    const float* ksn    = (const float*)d_in[7];
    const float* kgn    = (const float*)d_in[8];
    const float* vn     = (const float*)d_in[9];
    float* out = (float*)d_out;

    // Workspace regions (total 31.85 MB, under the 33.6 MB proven in round 2):
    //  [0, 12.58M)          qkv [2048][3072] bf16
    //  [12.58M, 18.87M)     WcatT (6.29M) -> later Vg [16][64][2112] (4.33M)
    //  [18.87M, 23.20M)     Kc [16][2112][64] (4.33M) -> later WoT (2.10M)
    //  [23.20M, 27.39M)     Xb (4.19M) -> later attnO (4.19M)
    //  [27.39M, 31.59M)     Opart [16*16*2][64][64] bf16 (4.19M)
    //  [31.59M, 31.85M)     ml float2 [16*16*2][64] (256KB)
    char* ws = (char*)d_ws;
    unsigned short* qkv   = (unsigned short*)(ws);
    unsigned short* WcatT = (unsigned short*)(ws + 12582912);
    unsigned short* Vg    = (unsigned short*)(ws + 12582912);
    unsigned short* Kc    = (unsigned short*)(ws + 18874368);
    unsigned short* WoT   = (unsigned short*)(ws + 18874368);
    unsigned short* Xb    = (unsigned short*)(ws + 23199744);
    unsigned short* attnO = (unsigned short*)(ws + 23199744);
    unsigned short* Opart = (unsigned short*)(ws + 27394048);
    float2*         ml    = (float2*)(ws + 31588352);

    convert_x<<<2048, 256, 0, stream>>>(x, Xb);
    transpose_w<<<dim3(8, 16),  256, 0, stream>>>(wq_sem, WcatT,               512);
    transpose_w<<<dim3(8, 16),  256, 0, stream>>>(wk_sem, WcatT + 512  * 1024, 512);
    transpose_w<<<dim3(8, 16),  256, 0, stream>>>(wq_geo, WcatT + 1024 * 1024, 512);
    transpose_w<<<dim3(8, 16),  256, 0, stream>>>(wk_geo, WcatT + 1536 * 1024, 512);
    transpose_w<<<dim3(16, 16), 256, 0, stream>>>(wv,     WcatT + 2048 * 1024, 1024);

    gemm_proj<<<dim3(QKV_W / 128, TSEQ / 128), 256, 0, stream>>>(Xb, WcatT, qkv);
    rope_kernel<<<(TSEQ * 512) / 256, 256, 0, stream>>>((bf16*)qkv);

    prep_k<<<dim3(33, 16), 256, 0, stream>>>(qkv, ksn, kgn, Kc);
    prep_v<<<dim3(33, 16), 256, 0, stream>>>(qkv, vn, Vg);

    attn_mfma<<<dim3(48, NHEAD), 256, 0, stream>>>(qkv, Kc, Vg, attnO, Opart, ml);
    combine_split<<<256, 256, 0, stream>>>(Opart, ml, attnO);

    transpose_w<<<dim3(16, 16), 256, 0, stream>>>(wo, WoT, 1024);
    gemm_out<<<dim3(DMODEL / 128, TSEQ / 128), 256, 0, stream>>>(attnO, WoT, out);
}

// Round 6
// 138.144 us; speedup vs baseline: 5.6750x; 1.0392x over previous
//
#include <hip/hip_runtime.h>
#include <hip/hip_bf16.h>

typedef __hip_bfloat16 bf16;
typedef __attribute__((ext_vector_type(8))) short bf16x8;   // 8 bf16 = 4 VGPR (MFMA A/B frag)
typedef __attribute__((ext_vector_type(4))) float f32x4;    // MFMA C/D frag

#define TSEQ   2048
#define DMODEL 1024
#define NHEAD  16
#define QKV_W  3072   // [0,512) qs | [512,1024) ks | [1024,1536) qg | [1536,2048) kg | [2048,3072) v
#define KST    2112   // padded key count (2049 real, zero-padded), 33*64
#define SCALE  0.17677669529663687f  // 1/sqrt(32) == sem_scale == geo_scale
#define LN1E4_16 0.5756462732485115f // ln(10000)/16

__device__ __forceinline__ unsigned short f2bf(float f) {
    union { bf16 h; unsigned short u; } x;
    x.h = __float2bfloat16(f);
    return x.u;
}
__device__ __forceinline__ float bf2f(unsigned short u) {
    return __uint_as_float(((unsigned int)u) << 16);
}

__device__ __forceinline__ void gload_lds16(const void* g, void* l) {
    __builtin_amdgcn_global_load_lds(
        (const __attribute__((address_space(1))) void*)g,
        (__attribute__((address_space(3))) void*)l, 16, 0, 0);
}

// ---------------------------------------------------------------------------
// Prep: f32 -> bf16 convert of X
// ---------------------------------------------------------------------------
__global__ __launch_bounds__(256) void convert_x(const float* __restrict__ X,
                                                 unsigned short* __restrict__ Xb)
{
    int i = (blockIdx.x * 256 + threadIdx.x) * 4;
    float4 v = *(const float4*)(X + i);
    ushort4 o;
    o.x = f2bf(v.x); o.y = f2bf(v.y); o.z = f2bf(v.z); o.w = f2bf(v.w);
    *(ushort4*)(Xb + i) = o;
}

// ---------------------------------------------------------------------------
// Prep: all 6 weight transposes in one launch (blockIdx.z selects weight).
// dst[C][1024] (bf16) = src[1024][C]^T
// ---------------------------------------------------------------------------
__global__ __launch_bounds__(256) void transpose_all(
    const float* __restrict__ wqs, const float* __restrict__ wks,
    const float* __restrict__ wqg, const float* __restrict__ wkg,
    const float* __restrict__ wv,  const float* __restrict__ wo,
    unsigned short* __restrict__ WcatT, unsigned short* __restrict__ WoT)
{
    __shared__ float T[64][65];
    const float* src; unsigned short* dst; int C;
    switch (blockIdx.z) {
        case 0: src = wqs; dst = WcatT;               C = 512;  break;
        case 1: src = wks; dst = WcatT + 512  * 1024; C = 512;  break;
        case 2: src = wqg; dst = WcatT + 1024 * 1024; C = 512;  break;
        case 3: src = wkg; dst = WcatT + 1536 * 1024; C = 512;  break;
        case 4: src = wv;  dst = WcatT + 2048 * 1024; C = 1024; break;
        default: src = wo; dst = WoT;                 C = 1024; break;
    }
    const int c0 = blockIdx.x * 64;
    if (c0 >= C) return;
    const int r0 = blockIdx.y * 64;
    const int tid = threadIdx.x;
    #pragma unroll
    for (int i = 0; i < 16; ++i) {
        int idx = tid + 256 * i;
        int r = idx >> 6, c = idx & 63;
        T[r][c] = src[(size_t)(r0 + r) * C + c0 + c];
    }
    __syncthreads();
    #pragma unroll
    for (int i = 0; i < 16; ++i) {
        int idx = tid + 256 * i;
        int cc = idx >> 6, rr = idx & 63;
        dst[(size_t)(c0 + cc) * 1024 + r0 + rr] = f2bf(T[rr][cc]);
    }
}

// ---------------------------------------------------------------------------
// Prep: Qc[h][q][64] = [qs | rope(qg)] combined, contiguous per row.
// ---------------------------------------------------------------------------
__global__ __launch_bounds__(256) void prep_q(
    const unsigned short* __restrict__ qkv,
    unsigned short* __restrict__ Qc)
{
    const int h = blockIdx.y, qt = blockIdx.x;
    const int tid = threadIdx.x;
    const int d = tid & 63;
    #pragma unroll
    for (int i = 0; i < 16; ++i) {
        int q = qt * 64 + i * 4 + (tid >> 6);
        float val;
        if (d < 32) {
            val = bf2f(qkv[(size_t)q * QKV_W + h * 32 + d]);
        } else {
            int ir = (d - 32) & 15;
            float inv = __expf(-(float)ir * LN1E4_16);
            float s, c;
            __sincosf((float)q * inv, &s, &c);
            float x1 = bf2f(qkv[(size_t)q * QKV_W + 1024 + h * 32 + ir]);
            float x2 = bf2f(qkv[(size_t)q * QKV_W + 1024 + h * 32 + ir + 16]);
            val = (d < 48) ? (x1 * c - x2 * s) : (x2 * c + x1 * s);
        }
        Qc[((size_t)h * TSEQ + q) * 64 + d] = f2bf(val);
    }
}

// ---------------------------------------------------------------------------
// Prep: Kc[h][fk][64] = [ks | rope(kg)]; fk=0 null (no rope), [1,2048] real,
// [2049,2112) zero.
// ---------------------------------------------------------------------------
__global__ __launch_bounds__(256) void prep_k(
    const unsigned short* __restrict__ qkv,
    const float* __restrict__ ksn, const float* __restrict__ kgn,
    unsigned short* __restrict__ Kc)
{
    const int h = blockIdx.y, ft = blockIdx.x;   // ft < 33
    const int tid = threadIdx.x;
    const int d = tid & 63;
    #pragma unroll
    for (int i = 0; i < 16; ++i) {
        int fk = ft * 64 + i * 4 + (tid >> 6);
        float val;
        if (fk == 0)
            val = (d < 32) ? ksn[h * 32 + d] : kgn[h * 32 + d - 32];
        else if (fk <= TSEQ) {
            int t = fk - 1;
            if (d < 32) {
                val = bf2f(qkv[(size_t)t * QKV_W + 512 + h * 32 + d]);
            } else {
                int ir = (d - 32) & 15;
                float inv = __expf(-(float)ir * LN1E4_16);
                float s, c;
                __sincosf((float)t * inv, &s, &c);
                float x1 = bf2f(qkv[(size_t)t * QKV_W + 1536 + h * 32 + ir]);
                float x2 = bf2f(qkv[(size_t)t * QKV_W + 1536 + h * 32 + ir + 16]);
                val = (d < 48) ? (x1 * c - x2 * s) : (x2 * c + x1 * s);
            }
        } else val = 0.0f;
        Kc[((size_t)h * KST + fk) * 64 + d] = f2bf(val);
    }
}

// ---------------------------------------------------------------------------
// Prep: Vg[h][dv][fk] = V^T per head, fk=0 null, zero-padded to KST.
// ---------------------------------------------------------------------------
__global__ __launch_bounds__(256) void prep_v(
    const unsigned short* __restrict__ qkv, const float* __restrict__ vn,
    unsigned short* __restrict__ Vg)
{
    __shared__ unsigned short T[64][65];
    const int h = blockIdx.y, ft = blockIdx.x;   // ft < 33
    const int tid = threadIdx.x;
    #pragma unroll
    for (int i = 0; i < 16; ++i) {
        int idx = tid + 256 * i;
        int fkl = idx >> 6, dv = idx & 63;
        int fk = ft * 64 + fkl;
        unsigned short u;
        if (fk == 0)           u = f2bf(vn[h * 64 + dv]);
        else if (fk <= TSEQ)   u = qkv[(size_t)(fk - 1) * QKV_W + 2048 + h * 64 + dv];
        else                   u = 0;
        T[fkl][dv] = u;
    }
    __syncthreads();
    #pragma unroll
    for (int i = 0; i < 16; ++i) {
        int idx = tid + 256 * i;
        int dv = idx >> 6, fkl = idx & 63;
        Vg[((size_t)h * 64 + dv) * KST + ft * 64 + fkl] = T[fkl][dv];
    }
}

// ---------------------------------------------------------------------------
// MFMA GEMM (m97 structure): 128x128 tile, BK=32, 4 waves, 4x4 16x16x32 frags.
// ---------------------------------------------------------------------------
__global__ __launch_bounds__(256) void gemm_proj(const unsigned short* __restrict__ A,
                                                 const unsigned short* __restrict__ Bt,
                                                 unsigned short* __restrict__ C)
{
    __shared__ __align__(16) unsigned short Abuf[128 * 32];
    __shared__ __align__(16) unsigned short Bbuf[128 * 32];
    const int n0 = blockIdx.x * 128, m0 = blockIdx.y * 128;
    const int tid = threadIdx.x, l = tid & 63, wv = tid >> 6;
    const int wr = wv >> 1, wc = wv & 1;
    const int lr = l & 15, kf = (l >> 4) * 8;

    f32x4 acc[4][4];
    #pragma unroll
    for (int i = 0; i < 4; ++i)
        #pragma unroll
        for (int j = 0; j < 4; ++j) acc[i][j] = (f32x4){0.f, 0.f, 0.f, 0.f};

    for (int k0 = 0; k0 < 1024; k0 += 32) {
        #pragma unroll
        for (int it = 0; it < 2; ++it) {
            int c = it * 256 + wv * 64 + l;
            int row = c >> 2, seg = c & 3;
            gload_lds16(A  + (size_t)(m0 + row) * 1024 + k0 + seg * 8,
                        &Abuf[(it * 256 + wv * 64) * 8]);
            gload_lds16(Bt + (size_t)(n0 + row) * 1024 + k0 + seg * 8,
                        &Bbuf[(it * 256 + wv * 64) * 8]);
        }
        __syncthreads();
        bf16x8 af[4], bfv[4];
        #pragma unroll
        for (int mf = 0; mf < 4; ++mf)
            af[mf] = *(const bf16x8*)&Abuf[(wr * 64 + mf * 16 + lr) * 32 + kf];
        #pragma unroll
        for (int nf = 0; nf < 4; ++nf)
            bfv[nf] = *(const bf16x8*)&Bbuf[(wc * 64 + nf * 16 + lr) * 32 + kf];
        #pragma unroll
        for (int mf = 0; mf < 4; ++mf)
            #pragma unroll
            for (int nf = 0; nf < 4; ++nf)
                acc[mf][nf] = __builtin_amdgcn_mfma_f32_16x16x32_bf16(
                    af[mf], bfv[nf], acc[mf][nf], 0, 0, 0);
        __syncthreads();
    }
    #pragma unroll
    for (int mf = 0; mf < 4; ++mf)
        #pragma unroll
        for (int nf = 0; nf < 4; ++nf)
            #pragma unroll
            for (int reg = 0; reg < 4; ++reg) {
                int row = m0 + wr * 64 + mf * 16 + (l >> 4) * 4 + reg;
                int col = n0 + wc * 64 + nf * 16 + lr;
                C[(size_t)row * QKV_W + col] = f2bf(acc[mf][nf][reg]);
            }
}

__global__ __launch_bounds__(256) void gemm_out(const unsigned short* __restrict__ A,
                                                const unsigned short* __restrict__ Bt,
                                                float* __restrict__ C)
{
    __shared__ __align__(16) unsigned short Abuf[128 * 32];
    __shared__ __align__(16) unsigned short Bbuf[128 * 32];
    const int n0 = blockIdx.x * 128, m0 = blockIdx.y * 128;
    const int tid = threadIdx.x, l = tid & 63, wv = tid >> 6;
    const int wr = wv >> 1, wc = wv & 1;
    const int lr = l & 15, kf = (l >> 4) * 8;

    f32x4 acc[4][4];
    #pragma unroll
    for (int i = 0; i < 4; ++i)
        #pragma unroll
        for (int j = 0; j < 4; ++j) acc[i][j] = (f32x4){0.f, 0.f, 0.f, 0.f};

    for (int k0 = 0; k0 < 1024; k0 += 32) {
        #pragma unroll
        for (int it = 0; it < 2; ++it) {
            int c = it * 256 + wv * 64 + l;
            int row = c >> 2, seg = c & 3;
            gload_lds16(A  + (size_t)(m0 + row) * 1024 + k0 + seg * 8,
                        &Abuf[(it * 256 + wv * 64) * 8]);
            gload_lds16(Bt + (size_t)(n0 + row) * 1024 + k0 + seg * 8,
                        &Bbuf[(it * 256 + wv * 64) * 8]);
        }
        __syncthreads();
        bf16x8 af[4], bfv[4];
        #pragma unroll
        for (int mf = 0; mf < 4; ++mf)
            af[mf] = *(const bf16x8*)&Abuf[(wr * 64 + mf * 16 + lr) * 32 + kf];
        #pragma unroll
        for (int nf = 0; nf < 4; ++nf)
            bfv[nf] = *(const bf16x8*)&Bbuf[(wc * 64 + nf * 16 + lr) * 32 + kf];
        #pragma unroll
        for (int mf = 0; mf < 4; ++mf)
            #pragma unroll
            for (int nf = 0; nf < 4; ++nf)
                acc[mf][nf] = __builtin_amdgcn_mfma_f32_16x16x32_bf16(
                    af[mf], bfv[nf], acc[mf][nf], 0, 0, 0);
        __syncthreads();
    }
    #pragma unroll
    for (int mf = 0; mf < 4; ++mf)
        #pragma unroll
        for (int nf = 0; nf < 4; ++nf)
            #pragma unroll
            for (int reg = 0; reg < 4; ++reg) {
                int row = m0 + wr * 64 + mf * 16 + (l >> 4) * 4 + reg;
                int col = n0 + wc * 64 + nf * 16 + lr;
                C[(size_t)row * DMODEL + col] = acc[mf][nf][reg];
            }
}

// ---------------------------------------------------------------------------
// MFMA flash attention, SWAPPED operands: S^T = mfma(K,Q), O^T = mfma(V^T,P).
// Each lane owns ONE q (= lane&15): softmax reduce = in-lane tree + 2 shfl.
// 2-way split-K for heavy blocks; double-buffered gload_lds staging with the
// XOR swizzle folded into the per-lane SOURCE address (rule #21).
// ---------------------------------------------------------------------------
__global__ __launch_bounds__(256) void attn_mfma(
    const unsigned short* __restrict__ Qc,
    const unsigned short* __restrict__ Kc,
    const unsigned short* __restrict__ Vg,
    unsigned short* __restrict__ attnO,
    unsigned short* __restrict__ Opart,
    float2* __restrict__ ml)
{
    __shared__ __align__(16) unsigned short KsL[2][64 * 64];
    __shared__ __align__(16) unsigned short VsL[2][64 * 64];
    __shared__ __align__(16) unsigned short Ps[64 * 64];

    const int h = blockIdx.y;
    int qb, t0, t1, part;
    bool split;
    {
        int i = blockIdx.x;
        if (i < 32) {
            split = true; qb = 31 - (i >> 1); part = i & 1;
            int nk = qb + 2, half = nk >> 1;
            t0 = part ? half : 0;
            t1 = part ? nk : half;
        } else {
            split = false; qb = 47 - i; part = 0;
            t0 = 0; t1 = qb + 2;
        }
    }
    const int q0 = qb * 64;
    const int tid = threadIdx.x, l = tid & 63, w = tid >> 6;
    const int lr = l & 15, lg = l >> 4;

    // Q fragment (as MFMA B operand; same per-lane contents as A-frag)
    const int qrow = q0 + w * 16 + lr;
    const int d0 = lg * 8;
    bf16x8 qa0 = *(const bf16x8*)&Qc[((size_t)h * TSEQ + qrow) * 64 + d0];
    bf16x8 qa1 = *(const bf16x8*)&Qc[((size_t)h * TSEQ + qrow) * 64 + 32 + d0];

    const int sc8 = (((l & 7) ^ ((l >> 3) & 7))) * 8;
    const int r0s = (w * 2 + 0) * 8 + (l >> 3);
    const int r1s = (w * 2 + 1) * 8 + (l >> 3);
    const unsigned short* Kh = Kc + (((size_t)h * KST) << 6);
    const unsigned short* Vh = Vg + (size_t)h * 64 * KST;

#define STAGE_KV(bufi, fk0_) do {                                              \
        gload_lds16(Kh + (((size_t)((fk0_) + r0s)) << 6) + sc8,                \
                    &KsL[bufi][(w * 2 + 0) * 512]);                            \
        gload_lds16(Kh + (((size_t)((fk0_) + r1s)) << 6) + sc8,                \
                    &KsL[bufi][(w * 2 + 1) * 512]);                            \
        gload_lds16(Vh + (size_t)r0s * KST + (fk0_) + sc8,                     \
                    &VsL[bufi][(w * 2 + 0) * 512]);                            \
        gload_lds16(Vh + (size_t)r1s * KST + (fk0_) + sc8,                     \
                    &VsL[bufi][(w * 2 + 1) * 512]);                            \
    } while (0)

    f32x4 o[4];
    #pragma unroll
    for (int i = 0; i < 4; ++i) o[i] = (f32x4){0.f, 0.f, 0.f, 0.f};
    float m = -1e30f, ll = 0.0f;
    const int q = qrow;   // this lane's query row

    int buf = 0;
    STAGE_KV(0, t0 * 64);
    asm volatile("s_waitcnt vmcnt(0)" ::: "memory");
    __builtin_amdgcn_s_barrier();

    for (int kb = t0; kb < t1; ++kb) {
        const int fk0 = kb * 64;
        if (kb + 1 < t1) STAGE_KV(buf ^ 1, fk0 + 64);   // prefetch next tile

        const unsigned short* Ksb = &KsL[buf][0];
        const unsigned short* Vsb = &VsL[buf][0];

        // ---- S^T = K Q^T : lane holds S[kk = nf*16 + lg*4 + reg][q]
        f32x4 sa[4];
        #pragma unroll
        for (int i = 0; i < 4; ++i) sa[i] = (f32x4){0.f, 0.f, 0.f, 0.f};
        __builtin_amdgcn_s_setprio(1);
        #pragma unroll
        for (int ks = 0; ks < 2; ++ks) {
            int dd = lg * 8 + ks * 32;
            bf16x8 qa = ks ? qa1 : qa0;
            #pragma unroll
            for (int nf = 0; nf < 4; ++nf) {
                int kkc = nf * 16 + lr;
                bf16x8 kbf = *(const bf16x8*)&Ksb[kkc * 64 + (dd ^ ((kkc & 7) << 3))];
                sa[nf] = __builtin_amdgcn_mfma_f32_16x16x32_bf16(kbf, qa, sa[nf], 0, 0, 0);
            }
        }
        __builtin_amdgcn_s_setprio(0);

        // ---- mask + scale; in-lane tree max + 2-stage shfl
        float sv[4][4];
        float mt = -1e30f;
        #pragma unroll
        for (int nf = 0; nf < 4; ++nf)
            #pragma unroll
            for (int reg = 0; reg < 4; ++reg) {
                int fk = fk0 + nf * 16 + lg * 4 + reg;
                float val = (fk <= q + 1) ? sa[nf][reg] * SCALE : -1e9f;
                sv[nf][reg] = val;
                mt = fmaxf(mt, val);
            }
        mt = fmaxf(mt, __shfl_xor(mt, 16, 64));
        mt = fmaxf(mt, __shfl_xor(mt, 32, 64));
        float mn = fmaxf(m, mt);
        float alpha = __expf(m - mn);
        m = mn;
        float rs = 0.0f;
        #pragma unroll
        for (int nf = 0; nf < 4; ++nf)
            #pragma unroll
            for (int reg = 0; reg < 4; ++reg) {
                float p = __expf(sv[nf][reg] - m);
                sv[nf][reg] = p;
                rs += p;
            }
        rs += __shfl_xor(rs, 16, 64);
        rs += __shfl_xor(rs, 32, 64);
        ll = ll * alpha + rs;
        #pragma unroll
        for (int nf = 0; nf < 4; ++nf)
            #pragma unroll
            for (int reg = 0; reg < 4; ++reg)
                o[nf][reg] *= alpha;

        // ---- P -> bf16 -> LDS (swizzled; wave-local rows: no barrier)
        #pragma unroll
        for (int nf = 0; nf < 4; ++nf)
            #pragma unroll
            for (int reg = 0; reg < 4; ++reg) {
                int r  = w * 16 + lr;
                int kk = nf * 16 + lg * 4 + reg;
                Ps[r * 64 + (kk ^ ((r & 7) << 3))] = f2bf(sv[nf][reg]);
            }

        // ---- O^T += V^T P^T : lane holds O[dv = nf*16+lg*4+reg][q]
        __builtin_amdgcn_s_setprio(1);
        #pragma unroll
        for (int ks = 0; ks < 2; ++ks) {
            int kk0 = lg * 8 + ks * 32;
            int pr  = w * 16 + lr;
            bf16x8 pa = *(const bf16x8*)&Ps[pr * 64 + (kk0 ^ ((pr & 7) << 3))];
            #pragma unroll
            for (int nf = 0; nf < 4; ++nf) {
                int dv = nf * 16 + lr;
                bf16x8 vb = *(const bf16x8*)&Vsb[dv * 64 + (kk0 ^ ((dv & 7) << 3))];
                o[nf] = __builtin_amdgcn_mfma_f32_16x16x32_bf16(vb, pa, o[nf], 0, 0, 0);
            }
        }
        __builtin_amdgcn_s_setprio(0);

        asm volatile("s_waitcnt vmcnt(0)" ::: "memory");
        __builtin_amdgcn_s_barrier();
        buf ^= 1;
    }
#undef STAGE_KV

    const float inv = 1.0f / ll;
    if (!split) {
        #pragma unroll
        for (int nf = 0; nf < 4; ++nf)
            #pragma unroll
            for (int reg = 0; reg < 4; ++reg) {
                int dv = nf * 16 + lg * 4 + reg;
                attnO[(size_t)q * DMODEL + h * 64 + dv] = f2bf(o[nf][reg] * inv);
            }
    } else {
        const int sidx = (h * 16 + (qb - 16)) * 2 + part;
        unsigned short* Od = Opart + (size_t)sidx * 4096;
        const int r = w * 16 + lr;
        #pragma unroll
        for (int nf = 0; nf < 4; ++nf)
            #pragma unroll
            for (int reg = 0; reg < 4; ++reg) {
                int dv = nf * 16 + lg * 4 + reg;
                Od[r * 64 + dv] = f2bf(o[nf][reg] * inv);
            }
        if (lg == 0)
            ml[sidx * 64 + r] = make_float2(m, ll);
    }
}

// ---------------------------------------------------------------------------
// Combine split-K partials for qb in [16,32).
// ---------------------------------------------------------------------------
__global__ __launch_bounds__(256) void combine_split(
    const unsigned short* __restrict__ Opart,
    const float2* __restrict__ ml,
    unsigned short* __restrict__ attnO)
{
    const int h = blockIdx.x >> 4, qs = blockIdx.x & 15;
    const int qb = 16 + qs;
    const int base = (h * 16 + qs) * 2;
    const unsigned short* O0 = Opart + (size_t)base * 4096;
    const unsigned short* O1 = O0 + 4096;
    const float2* ml0 = ml + base * 64;
    const float2* ml1 = ml0 + 64;
    const int t = threadIdx.x;
    const int dv = t & 63, rg = t >> 6;
    #pragma unroll
    for (int i = 0; i < 16; ++i) {
        int r = rg + i * 4;
        float2 a = ml0[r], b = ml1[r];
        float mm = fmaxf(a.x, b.x);
        float w0 = a.y * __expf(a.x - mm);
        float w1 = b.y * __expf(b.x - mm);
        float inv = 1.0f / (w0 + w1);
        float o0 = bf2f(O0[r * 64 + dv]);
        float o1 = bf2f(O1[r * 64 + dv]);
        int qq = qb * 64 + r;
        attnO[(size_t)qq * DMODEL + h * 64 + dv] = f2bf((w0 * o0 + w1 * o1) * inv);
    }
}

// ---------------------------------------------------------------------------
extern "C" void kernel_launch(void* const* d_in, const int* in_sizes, int n_in,
                              void* d_out, int out_size, void* d_ws, size_t ws_size,
                              hipStream_t stream)
{
    const float* x      = (const float*)d_in[0];
    const float* wq_sem = (const float*)d_in[1];
    const float* wk_sem = (const float*)d_in[2];
    const float* wq_geo = (const float*)d_in[3];
    const float* wk_geo = (const float*)d_in[4];
    const float* wv     = (const float*)d_in[5];
    const float* wo     = (const float*)d_in[6];
    const float* ksn    = (const float*)d_in[7];
    const float* kgn    = (const float*)d_in[8];
    const float* vn     = (const float*)d_in[9];
    float* out = (float*)d_out;

    // Workspace (peak 28.1 MiB, lifetime-based reuse):
    // Phase A (proj):  Xb [0,4.19M) | WcatT [4.19M,10.49M) | WoT [10.49M,12.58M) | qkv [12.58M,25.17M)
    // Phase B (preps): Vg [0,4.33M) | Qc [4.33M,8.52M) | Kc [25.17M,29.49M)   (Xb/WcatT dead)
    // Phase C (attn):  attnO [12.58M,16.78M) | Opart [16.78M,20.97M) | ml [20.97M,21.23M) (qkv dead)
    char* ws = (char*)d_ws;
    unsigned short* Xb    = (unsigned short*)(ws);
    unsigned short* WcatT = (unsigned short*)(ws + 4194304);
    unsigned short* WoT   = (unsigned short*)(ws + 10485760);
    unsigned short* qkv   = (unsigned short*)(ws + 12582912);
    unsigned short* Vg    = (unsigned short*)(ws);
    unsigned short* Qc    = (unsigned short*)(ws + 4325376);
    unsigned short* Kc    = (unsigned short*)(ws + 25165824);
    unsigned short* attnO = (unsigned short*)(ws + 12582912);
    unsigned short* Opart = (unsigned short*)(ws + 16777216);
    float2*         ml    = (float2*)(ws + 20971520);

    convert_x<<<2048, 256, 0, stream>>>(x, Xb);
    transpose_all<<<dim3(16, 16, 6), 256, 0, stream>>>(
        wq_sem, wk_sem, wq_geo, wk_geo, wv, wo, WcatT, WoT);

    gemm_proj<<<dim3(QKV_W / 128, TSEQ / 128), 256, 0, stream>>>(Xb, WcatT, qkv);

    prep_q<<<dim3(32, 16), 256, 0, stream>>>(qkv, Qc);
    prep_k<<<dim3(33, 16), 256, 0, stream>>>(qkv, ksn, kgn, Kc);
    prep_v<<<dim3(33, 16), 256, 0, stream>>>(qkv, vn, Vg);

    attn_mfma<<<dim3(48, NHEAD), 256, 0, stream>>>(Qc, Kc, Vg, attnO, Opart, ml);
    combine_split<<<256, 256, 0, stream>>>(Opart, ml, attnO);

    gemm_out<<<dim3(DMODEL / 128, TSEQ / 128), 256, 0, stream>>>(attnO, WoT, out);
}

// Round 7
// 97.317 us; speedup vs baseline: 8.0559x; 1.4195x over previous
//
#include <hip/hip_runtime.h>
#include <hip/hip_bf16.h>

typedef __hip_bfloat16 bf16;
typedef __attribute__((ext_vector_type(8))) short bf16x8;   // 8 bf16 = 4 VGPR (MFMA A/B frag)
typedef __attribute__((ext_vector_type(4))) short bf16x4;   // 4 bf16 = 8B
typedef __attribute__((ext_vector_type(4))) float f32x4;    // MFMA C/D frag

#define TSEQ   2048
#define DMODEL 1024
#define NHEAD  16
#define KST    2112   // padded key count (2049 real, zero-padded), 33*64
#define SCALE  0.17677669529663687f  // 1/sqrt(32) == sem_scale == geo_scale
#define LN1E4_16 0.5756462732485115f // ln(10000)/16

__device__ __forceinline__ unsigned short f2bf(float f) {
    union { bf16 h; unsigned short u; } x;
    x.h = __float2bfloat16(f);
    return x.u;
}
__device__ __forceinline__ float bf2f(unsigned short u) {
    return __uint_as_float(((unsigned int)u) << 16);
}

__device__ __forceinline__ void gload_lds16(const void* g, void* l) {
    __builtin_amdgcn_global_load_lds(
        (const __attribute__((address_space(1))) void*)g,
        (__attribute__((address_space(3))) void*)l, 16, 0, 0);
}

// ---------------------------------------------------------------------------
// Prep: f32 -> bf16 convert of X
// ---------------------------------------------------------------------------
__global__ __launch_bounds__(256) void convert_x(const float* __restrict__ X,
                                                 unsigned short* __restrict__ Xb)
{
    int i = (blockIdx.x * 256 + threadIdx.x) * 4;
    float4 v = *(const float4*)(X + i);
    ushort4 o;
    o.x = f2bf(v.x); o.y = f2bf(v.y); o.z = f2bf(v.z); o.w = f2bf(v.w);
    *(ushort4*)(Xb + i) = o;
}

// ---------------------------------------------------------------------------
// Prep: all 6 weight transposes in one launch. dst[C][1024] = src[1024][C]^T
// ---------------------------------------------------------------------------
__global__ __launch_bounds__(256) void transpose_all(
    const float* __restrict__ wqs, const float* __restrict__ wks,
    const float* __restrict__ wqg, const float* __restrict__ wkg,
    const float* __restrict__ wv,  const float* __restrict__ wo,
    unsigned short* __restrict__ WcatT, unsigned short* __restrict__ WoT)
{
    __shared__ float T[64][65];
    const float* src; unsigned short* dst; int C;
    switch (blockIdx.z) {
        case 0: src = wqs; dst = WcatT;               C = 512;  break;
        case 1: src = wks; dst = WcatT + 512  * 1024; C = 512;  break;
        case 2: src = wqg; dst = WcatT + 1024 * 1024; C = 512;  break;
        case 3: src = wkg; dst = WcatT + 1536 * 1024; C = 512;  break;
        case 4: src = wv;  dst = WcatT + 2048 * 1024; C = 1024; break;
        default: src = wo; dst = WoT;                 C = 1024; break;
    }
    const int c0 = blockIdx.x * 64;
    if (c0 >= C) return;
    const int r0 = blockIdx.y * 64;
    const int tid = threadIdx.x;
    #pragma unroll
    for (int i = 0; i < 16; ++i) {
        int idx = tid + 256 * i;
        int r = idx >> 6, c = idx & 63;
        T[r][c] = src[(size_t)(r0 + r) * C + c0 + c];
    }
    __syncthreads();
    #pragma unroll
    for (int i = 0; i < 16; ++i) {
        int idx = tid + 256 * i;
        int cc = idx >> 6, rr = idx & 63;
        dst[(size_t)(c0 + cc) * 1024 + r0 + rr] = f2bf(T[rr][cc]);
    }
}

// ---------------------------------------------------------------------------
// Prep: fill null rows (fk=0) and zero pads (fk in [2049,2112)) of Kc / Vg.
// Disjoint from gemm_proj_fused's writes (fk in [1,2048]).
// ---------------------------------------------------------------------------
__global__ __launch_bounds__(256) void init_null(
    const float* __restrict__ ksn, const float* __restrict__ kgn,
    const float* __restrict__ vn,
    unsigned short* __restrict__ Kc, unsigned short* __restrict__ Vg)
{
    const int h = blockIdx.x;
    const int tid = threadIdx.x;
    const int d = tid & 63, g = tid >> 6;
    if (g == 0)
        Kc[((size_t)h * KST + 0) * 64 + d] =
            f2bf(d < 32 ? ksn[h * 32 + d] : kgn[h * 32 + d - 32]);
    if (g == 1)
        Vg[((size_t)h * 64 + d) * KST + 0] = f2bf(vn[h * 64 + d]);
    for (int fk = 2049 + g; fk < KST; fk += 4) {
        Kc[((size_t)h * KST + fk) * 64 + d] = 0;
        Vg[((size_t)h * 64 + d) * KST + fk] = 0;
    }
}

// ---------------------------------------------------------------------------
// Fused projection GEMM: 64x128 tile (grid 24x32 = 768 blocks = 3/CU), BK=32.
// Epilogue writes directly into attention layouts:
//   sec 0: qs            -> Qc[h][q][d]        (pre-scaled by SCALE)
//   sec 1: ks            -> Kc[h][q+1][d]
//   sec 2: qg -> RoPE    -> Qc[h][q][32+ir]    (pre-scaled by SCALE)
//   sec 3: kg -> RoPE    -> Kc[h][q+1][32+ir]
//   sec 4/5: v           -> Vg[h][dv][q+1]  (V^T)
// RoPE pairs (ir, ir+16) live in the SAME lane, adjacent nf frags.
// ---------------------------------------------------------------------------
__global__ __launch_bounds__(256) void gemm_proj_fused(
    const unsigned short* __restrict__ A,   // Xb [2048][1024]
    const unsigned short* __restrict__ Bt,  // WcatT [3072][1024]
    unsigned short* __restrict__ Qc,
    unsigned short* __restrict__ Kc,
    unsigned short* __restrict__ Vg)
{
    __shared__ __align__(16) unsigned short Abuf[64 * 32];
    __shared__ __align__(16) unsigned short Bbuf[128 * 32];
    const int n0 = blockIdx.x * 128, m0 = blockIdx.y * 64;
    const int tid = threadIdx.x, l = tid & 63, wv = tid >> 6;
    const int wr = wv >> 1, wc = wv & 1;      // wave tile: 32 rows x 64 cols
    const int lr = l & 15, lg = l >> 4, kf = lg * 8;

    const int arow = wv * 16 + (l >> 2);
    const int aseg = (l & 3) * 8;

    f32x4 acc[2][4];
    #pragma unroll
    for (int i = 0; i < 2; ++i)
        #pragma unroll
        for (int j = 0; j < 4; ++j) acc[i][j] = (f32x4){0.f, 0.f, 0.f, 0.f};

    for (int k0 = 0; k0 < 1024; k0 += 32) {
        gload_lds16(A + (size_t)(m0 + arow) * 1024 + k0 + aseg, &Abuf[wv * 512]);
        #pragma unroll
        for (int it = 0; it < 2; ++it) {
            int brow = it * 64 + wv * 16 + (l >> 2);
            gload_lds16(Bt + (size_t)(n0 + brow) * 1024 + k0 + aseg,
                        &Bbuf[(it * 256 + wv * 64) * 8]);
        }
        __syncthreads();
        bf16x8 af[2], bfv[4];
        #pragma unroll
        for (int mf = 0; mf < 2; ++mf)
            af[mf] = *(const bf16x8*)&Abuf[(wr * 32 + mf * 16 + lr) * 32 + kf];
        #pragma unroll
        for (int nf = 0; nf < 4; ++nf)
            bfv[nf] = *(const bf16x8*)&Bbuf[(wc * 64 + nf * 16 + lr) * 32 + kf];
        #pragma unroll
        for (int mf = 0; mf < 2; ++mf)
            #pragma unroll
            for (int nf = 0; nf < 4; ++nf)
                acc[mf][nf] = __builtin_amdgcn_mfma_f32_16x16x32_bf16(
                    af[mf], bfv[nf], acc[mf][nf], 0, 0, 0);
        __syncthreads();
    }

    const int sec = n0 >> 9;   // 0 qs | 1 ks | 2 qg | 3 kg | 4,5 v
    if (sec <= 1) {
        unsigned short* dst = (sec == 0) ? Qc : Kc;
        const int tstr  = (sec == 0) ? TSEQ : KST;
        const int fkoff = (sec == 0) ? 0 : 1;
        const float sc  = (sec == 0) ? SCALE : 1.0f;
        #pragma unroll
        for (int mf = 0; mf < 2; ++mf)
            #pragma unroll
            for (int nf = 0; nf < 4; ++nf) {
                int col = (n0 & 511) + wc * 64 + nf * 16 + lr;
                int h = col >> 5, d = col & 31;
                #pragma unroll
                for (int reg = 0; reg < 4; ++reg) {
                    int q = m0 + wr * 32 + mf * 16 + lg * 4 + reg;
                    dst[((size_t)h * tstr + q + fkoff) * 64 + d] =
                        f2bf(acc[mf][nf][reg] * sc);
                }
            }
    } else if (sec <= 3) {
        unsigned short* dst = (sec == 2) ? Qc : Kc;
        const int tstr  = (sec == 2) ? TSEQ : KST;
        const int fkoff = (sec == 2) ? 0 : 1;
        const float sc  = (sec == 2) ? SCALE : 1.0f;
        const float invf = __expf(-(float)lr * LN1E4_16);
        #pragma unroll
        for (int mf = 0; mf < 2; ++mf)
            #pragma unroll
            for (int reg = 0; reg < 4; ++reg) {
                int q = m0 + wr * 32 + mf * 16 + lg * 4 + reg;
                float s, c;
                __sincosf((float)q * invf, &s, &c);
                #pragma unroll
                for (int nfp = 0; nfp < 2; ++nfp) {
                    int nf0 = nfp * 2;
                    int colbase = (n0 & 511) + wc * 64 + nf0 * 16;
                    int h = colbase >> 5;
                    float x1 = acc[mf][nf0][reg], x2 = acc[mf][nf0 + 1][reg];
                    size_t base = ((size_t)h * tstr + q + fkoff) * 64 + 32;
                    dst[base + lr]      = f2bf((x1 * c - x2 * s) * sc);
                    dst[base + lr + 16] = f2bf((x2 * c + x1 * s) * sc);
                }
            }
    } else {
        #pragma unroll
        for (int nf = 0; nf < 4; ++nf) {
            int colr = (n0 - 2048) + wc * 64 + nf * 16 + lr;
            int h = colr >> 6, dv = colr & 63;
            size_t rowbase = ((size_t)h * 64 + dv) * KST;
            #pragma unroll
            for (int mf = 0; mf < 2; ++mf)
                #pragma unroll
                for (int reg = 0; reg < 4; ++reg) {
                    int q = m0 + wr * 32 + mf * 16 + lg * 4 + reg;
                    Vg[rowbase + q + 1] = f2bf(acc[mf][nf][reg]);
                }
        }
    }
}

// ---------------------------------------------------------------------------
// Output GEMM: 64x64 tile (grid 16x32 = 512 blocks = 2/CU), BK=32.
// ---------------------------------------------------------------------------
__global__ __launch_bounds__(256) void gemm_out(const unsigned short* __restrict__ A,
                                                const unsigned short* __restrict__ Bt,
                                                float* __restrict__ C)
{
    __shared__ __align__(16) unsigned short Abuf[64 * 32];
    __shared__ __align__(16) unsigned short Bbuf[64 * 32];
    const int n0 = blockIdx.x * 64, m0 = blockIdx.y * 64;
    const int tid = threadIdx.x, l = tid & 63, wv = tid >> 6;
    const int wr = wv >> 1, wc = wv & 1;      // wave tile: 32 x 32
    const int lr = l & 15, lg = l >> 4, kf = lg * 8;

    const int arow = wv * 16 + (l >> 2);
    const int aseg = (l & 3) * 8;

    f32x4 acc[2][2];
    #pragma unroll
    for (int i = 0; i < 2; ++i)
        #pragma unroll
        for (int j = 0; j < 2; ++j) acc[i][j] = (f32x4){0.f, 0.f, 0.f, 0.f};

    for (int k0 = 0; k0 < 1024; k0 += 32) {
        gload_lds16(A  + (size_t)(m0 + arow) * 1024 + k0 + aseg, &Abuf[wv * 512]);
        gload_lds16(Bt + (size_t)(n0 + arow) * 1024 + k0 + aseg, &Bbuf[wv * 512]);
        __syncthreads();
        bf16x8 af[2], bfv[2];
        #pragma unroll
        for (int mf = 0; mf < 2; ++mf)
            af[mf] = *(const bf16x8*)&Abuf[(wr * 32 + mf * 16 + lr) * 32 + kf];
        #pragma unroll
        for (int nf = 0; nf < 2; ++nf)
            bfv[nf] = *(const bf16x8*)&Bbuf[(wc * 32 + nf * 16 + lr) * 32 + kf];
        #pragma unroll
        for (int mf = 0; mf < 2; ++mf)
            #pragma unroll
            for (int nf = 0; nf < 2; ++nf)
                acc[mf][nf] = __builtin_amdgcn_mfma_f32_16x16x32_bf16(
                    af[mf], bfv[nf], acc[mf][nf], 0, 0, 0);
        __syncthreads();
    }
    #pragma unroll
    for (int mf = 0; mf < 2; ++mf)
        #pragma unroll
        for (int nf = 0; nf < 2; ++nf)
            #pragma unroll
            for (int reg = 0; reg < 4; ++reg) {
                int row = m0 + wr * 32 + mf * 16 + lg * 4 + reg;
                int col = n0 + wc * 32 + nf * 16 + lr;
                C[(size_t)row * DMODEL + col] = acc[mf][nf][reg];
            }
}

// ---------------------------------------------------------------------------
// MFMA flash attention, SWAPPED operands: S^T = mfma(K,Q), O^T = mfma(V^T,P).
// Q pre-scaled by SCALE. Each lane owns ONE q (= lane&15). 2-way split-K for
// heavy blocks; double-buffered gload_lds staging, swizzle in SOURCE address.
// ---------------------------------------------------------------------------
__global__ __launch_bounds__(256) void attn_mfma(
    const unsigned short* __restrict__ Qc,
    const unsigned short* __restrict__ Kc,
    const unsigned short* __restrict__ Vg,
    unsigned short* __restrict__ attnO,
    unsigned short* __restrict__ Opart,
    float2* __restrict__ ml)
{
    __shared__ __align__(16) unsigned short KsL[2][64 * 64];
    __shared__ __align__(16) unsigned short VsL[2][64 * 64];
    __shared__ __align__(16) unsigned short Ps[64 * 64];

    const int h = blockIdx.y;
    int qb, t0, t1, part;
    bool split;
    {
        int i = blockIdx.x;
        if (i < 32) {
            split = true; qb = 31 - (i >> 1); part = i & 1;
            int nk = qb + 2, half = nk >> 1;
            t0 = part ? half : 0;
            t1 = part ? nk : half;
        } else {
            split = false; qb = 47 - i; part = 0;
            t0 = 0; t1 = qb + 2;
        }
    }
    const int q0 = qb * 64;
    const int tid = threadIdx.x, l = tid & 63, w = tid >> 6;
    const int lr = l & 15, lg = l >> 4;

    const int qrow = q0 + w * 16 + lr;
    const int d0 = lg * 8;
    bf16x8 qa0 = *(const bf16x8*)&Qc[((size_t)h * TSEQ + qrow) * 64 + d0];
    bf16x8 qa1 = *(const bf16x8*)&Qc[((size_t)h * TSEQ + qrow) * 64 + 32 + d0];

    const int sc8 = (((l & 7) ^ ((l >> 3) & 7))) * 8;
    const int r0s = (w * 2 + 0) * 8 + (l >> 3);
    const int r1s = (w * 2 + 1) * 8 + (l >> 3);
    const unsigned short* Kh = Kc + (((size_t)h * KST) << 6);
    const unsigned short* Vh = Vg + (size_t)h * 64 * KST;

#define STAGE_KV(bufi, fk0_) do {                                              \
        gload_lds16(Kh + (((size_t)((fk0_) + r0s)) << 6) + sc8,                \
                    &KsL[bufi][(w * 2 + 0) * 512]);                            \
        gload_lds16(Kh + (((size_t)((fk0_) + r1s)) << 6) + sc8,                \
                    &KsL[bufi][(w * 2 + 1) * 512]);                            \
        gload_lds16(Vh + (size_t)r0s * KST + (fk0_) + sc8,                     \
                    &VsL[bufi][(w * 2 + 0) * 512]);                            \
        gload_lds16(Vh + (size_t)r1s * KST + (fk0_) + sc8,                     \
                    &VsL[bufi][(w * 2 + 1) * 512]);                            \
    } while (0)

    f32x4 o[4];
    #pragma unroll
    for (int i = 0; i < 4; ++i) o[i] = (f32x4){0.f, 0.f, 0.f, 0.f};
    float m = -1e30f, ll = 0.0f;
    const int q = qrow;

    int buf = 0;
    STAGE_KV(0, t0 * 64);
    asm volatile("s_waitcnt vmcnt(0)" ::: "memory");
    __builtin_amdgcn_s_barrier();

    for (int kb = t0; kb < t1; ++kb) {
        const int fk0 = kb * 64;
        if (kb + 1 < t1) STAGE_KV(buf ^ 1, fk0 + 64);

        const unsigned short* Ksb = &KsL[buf][0];
        const unsigned short* Vsb = &VsL[buf][0];

        // ---- S^T = K Q^T
        f32x4 sa[4];
        #pragma unroll
        for (int i = 0; i < 4; ++i) sa[i] = (f32x4){0.f, 0.f, 0.f, 0.f};
        __builtin_amdgcn_s_setprio(1);
        #pragma unroll
        for (int ks = 0; ks < 2; ++ks) {
            int dd = lg * 8 + ks * 32;
            bf16x8 qa = ks ? qa1 : qa0;
            #pragma unroll
            for (int nf = 0; nf < 4; ++nf) {
                int kkc = nf * 16 + lr;
                bf16x8 kbf = *(const bf16x8*)&Ksb[kkc * 64 + (dd ^ ((kkc & 7) << 3))];
                sa[nf] = __builtin_amdgcn_mfma_f32_16x16x32_bf16(kbf, qa, sa[nf], 0, 0, 0);
            }
        }
        __builtin_amdgcn_s_setprio(0);

        // ---- mask; in-lane tree max + 2-stage shfl (Q pre-scaled)
        float sv[4][4];
        float mt = -1e30f;
        #pragma unroll
        for (int nf = 0; nf < 4; ++nf)
            #pragma unroll
            for (int reg = 0; reg < 4; ++reg) {
                int fk = fk0 + nf * 16 + lg * 4 + reg;
                float val = (fk <= q + 1) ? sa[nf][reg] : -1e9f;
                sv[nf][reg] = val;
                mt = fmaxf(mt, val);
            }
        mt = fmaxf(mt, __shfl_xor(mt, 16, 64));
        mt = fmaxf(mt, __shfl_xor(mt, 32, 64));
        float mn = fmaxf(m, mt);
        float alpha = __expf(m - mn);
        m = mn;
        float rs = 0.0f;
        #pragma unroll
        for (int nf = 0; nf < 4; ++nf)
            #pragma unroll
            for (int reg = 0; reg < 4; ++reg) {
                float p = __expf(sv[nf][reg] - m);
                sv[nf][reg] = p;
                rs += p;
            }
        rs += __shfl_xor(rs, 16, 64);
        rs += __shfl_xor(rs, 32, 64);
        ll = ll * alpha + rs;
        #pragma unroll
        for (int nf = 0; nf < 4; ++nf)
            #pragma unroll
            for (int reg = 0; reg < 4; ++reg)
                o[nf][reg] *= alpha;

        // ---- P -> bf16 -> LDS, packed b64 (4 consecutive kk stay contiguous
        //      under the 16B-granule XOR swizzle; 8B aligned)
        {
            int r = w * 16 + lr;
            #pragma unroll
            for (int nf = 0; nf < 4; ++nf) {
                bf16x4 pk;
                pk[0] = f2bf(sv[nf][0]); pk[1] = f2bf(sv[nf][1]);
                pk[2] = f2bf(sv[nf][2]); pk[3] = f2bf(sv[nf][3]);
                int kk0 = nf * 16 + lg * 4;
                *(bf16x4*)&Ps[r * 64 + (kk0 ^ ((r & 7) << 3))] = pk;
            }
        }

        // ---- O^T += V^T P^T
        __builtin_amdgcn_s_setprio(1);
        #pragma unroll
        for (int ks = 0; ks < 2; ++ks) {
            int kk0 = lg * 8 + ks * 32;
            int pr  = w * 16 + lr;
            bf16x8 pa = *(const bf16x8*)&Ps[pr * 64 + (kk0 ^ ((pr & 7) << 3))];
            #pragma unroll
            for (int nf = 0; nf < 4; ++nf) {
                int dv = nf * 16 + lr;
                bf16x8 vb = *(const bf16x8*)&Vsb[dv * 64 + (kk0 ^ ((dv & 7) << 3))];
                o[nf] = __builtin_amdgcn_mfma_f32_16x16x32_bf16(vb, pa, o[nf], 0, 0, 0);
            }
        }
        __builtin_amdgcn_s_setprio(0);

        asm volatile("s_waitcnt vmcnt(0)" ::: "memory");
        __builtin_amdgcn_s_barrier();
        buf ^= 1;
    }
#undef STAGE_KV

    const float inv = 1.0f / ll;
    if (!split) {
        #pragma unroll
        for (int nf = 0; nf < 4; ++nf)
            #pragma unroll
            for (int reg = 0; reg < 4; ++reg) {
                int dv = nf * 16 + lg * 4 + reg;
                attnO[(size_t)q * DMODEL + h * 64 + dv] = f2bf(o[nf][reg] * inv);
            }
    } else {
        const int sidx = (h * 16 + (qb - 16)) * 2 + part;
        unsigned short* Od = Opart + (size_t)sidx * 4096;
        const int r = w * 16 + lr;
        #pragma unroll
        for (int nf = 0; nf < 4; ++nf)
            #pragma unroll
            for (int reg = 0; reg < 4; ++reg) {
                int dv = nf * 16 + lg * 4 + reg;
                Od[r * 64 + dv] = f2bf(o[nf][reg] * inv);
            }
        if (lg == 0)
            ml[sidx * 64 + r] = make_float2(m, ll);
    }
}

// ---------------------------------------------------------------------------
// Combine split-K partials for qb in [16,32).
// ---------------------------------------------------------------------------
__global__ __launch_bounds__(256) void combine_split(
    const unsigned short* __restrict__ Opart,
    const float2* __restrict__ ml,
    unsigned short* __restrict__ attnO)
{
    const int h = blockIdx.x >> 4, qs = blockIdx.x & 15;
    const int qb = 16 + qs;
    const int base = (h * 16 + qs) * 2;
    const unsigned short* O0 = Opart + (size_t)base * 4096;
    const unsigned short* O1 = O0 + 4096;
    const float2* ml0 = ml + base * 64;
    const float2* ml1 = ml0 + 64;
    const int t = threadIdx.x;
    const int dv = t & 63, rg = t >> 6;
    #pragma unroll
    for (int i = 0; i < 16; ++i) {
        int r = rg + i * 4;
        float2 a = ml0[r], b = ml1[r];
        float mm = fmaxf(a.x, b.x);
        float w0 = a.y * __expf(a.x - mm);
        float w1 = b.y * __expf(b.x - mm);
        float inv = 1.0f / (w0 + w1);
        float o0 = bf2f(O0[r * 64 + dv]);
        float o1 = bf2f(O1[r * 64 + dv]);
        int qq = qb * 64 + r;
        attnO[(size_t)qq * DMODEL + h * 64 + dv] = f2bf((w0 * o0 + w1 * o1) * inv);
    }
}

// ---------------------------------------------------------------------------
extern "C" void kernel_launch(void* const* d_in, const int* in_sizes, int n_in,
                              void* d_out, int out_size, void* d_ws, size_t ws_size,
                              hipStream_t stream)
{
    const float* x      = (const float*)d_in[0];
    const float* wq_sem = (const float*)d_in[1];
    const float* wk_sem = (const float*)d_in[2];
    const float* wq_geo = (const float*)d_in[3];
    const float* wk_geo = (const float*)d_in[4];
    const float* wv     = (const float*)d_in[5];
    const float* wo     = (const float*)d_in[6];
    const float* ksn    = (const float*)d_in[7];
    const float* kgn    = (const float*)d_in[8];
    const float* vn     = (const float*)d_in[9];
    float* out = (float*)d_out;

    // Workspace (peak 29.9 MB; Xb reused as attnO after gemm_proj_fused):
    //  [0,        4.19M)  Xb            -> attnO
    //  [4.19M,   10.49M)  WcatT
    //  [10.49M,  12.58M)  WoT
    //  [12.58M,  16.78M)  Qc  [16][2048][64]
    //  [16.78M,  21.10M)  Kc  [16][2112][64]
    //  [21.10M,  25.43M)  Vg  [16][64][2112]
    //  [25.43M,  29.62M)  Opart [512][64][64]
    //  [29.62M,  29.88M)  ml  float2 [512][64]
    char* ws = (char*)d_ws;
    unsigned short* Xb    = (unsigned short*)(ws);
    unsigned short* attnO = (unsigned short*)(ws);
    unsigned short* WcatT = (unsigned short*)(ws + 4194304);
    unsigned short* WoT   = (unsigned short*)(ws + 10485760);
    unsigned short* Qc    = (unsigned short*)(ws + 12582912);
    unsigned short* Kc    = (unsigned short*)(ws + 16777216);
    unsigned short* Vg    = (unsigned short*)(ws + 21102592);
    unsigned short* Opart = (unsigned short*)(ws + 25427968);
    float2*         ml    = (float2*)(ws + 29622272);

    convert_x<<<2048, 256, 0, stream>>>(x, Xb);
    transpose_all<<<dim3(16, 16, 6), 256, 0, stream>>>(
        wq_sem, wk_sem, wq_geo, wk_geo, wv, wo, WcatT, WoT);
    init_null<<<16, 256, 0, stream>>>(ksn, kgn, vn, Kc, Vg);

    gemm_proj_fused<<<dim3(24, 32), 256, 0, stream>>>(Xb, WcatT, Qc, Kc, Vg);

    attn_mfma<<<dim3(48, NHEAD), 256, 0, stream>>>(Qc, Kc, Vg, attnO, Opart, ml);
    combine_split<<<256, 256, 0, stream>>>(Opart, ml, attnO);

    gemm_out<<<dim3(16, 32), 256, 0, stream>>>(attnO, WoT, out);
}